// Round 15
// baseline (101.601 us; speedup 1.0000x reference)
//
#include <hip/hip_runtime.h>

// InteractionLayer (SchNet-style) — MFMA f16, persistent 2-row blocks. gfx950.
// Shapes hardcoded: B=4, N=256, NF=H=128, K=300, gamma=10, dk=0.1.
// GRID = 512 blocks x 512 threads = EXACTLY the resident capacity (2 blocks/CU
// x 256 CU): one dispatch wave, zero mid-kernel refill. Each block processes
// rows bid and bid+512 sequentially; W2pk staged ONCE per block (amortized),
// row-1 prologue replaces a cold re-dispatch. [round-14 analysis: 16-wave/CU
// residency is register-quantization-pinned (96 regs -> 4 waves/SIMD); the
// remaining structural loss was dispatch raggedness.]
// Per row (identical to proven round-14 kernel, 50.3 us):
//  - parallel rank-sort of j by window center (512 thr x 128 scans);
//  - GEMM1: rbf[64j x 320k] @ (log2e*W1)[320x128] f16 MFMA; rbf via exact
//    exp-recurrence in regs; K-steps per sorted 16-row group (window +-12,
//    n in {1,2,3}); straight-line n=1/2 + rare tail; B-frags from global.
//  - ssp in log2 domain with log2e folded into W1pk: y' = log2(0.5*2^acc+0.5),
//    no per-element multiply; GEMM2: y' @ W2 (LDS-staged) -> ssp_l2p -> sum_j
//    in log2 domain, ln2 applied once in the reduction.
//  - main loop: 1 barrier/chunk via ytile double-buffer.
//
// MFMA 16x16x32 layouts (gfx950):
//   A: lane l elem j -> A[l&15][(l>>4)*8 + j]
//   B: lane l elem j -> B[(l>>4)*8 + j][l&15]
//   D: lane l reg  r -> D[(l>>4)*4 + r][l&15]

typedef _Float16 f16x8 __attribute__((ext_vector_type(8)));
typedef _Float16 f16x2 __attribute__((ext_vector_type(2)));
typedef float f32x4 __attribute__((ext_vector_type(4)));

__device__ __forceinline__ float exp2f_fast(float x) {
#if __has_builtin(__builtin_amdgcn_exp2f)
  return __builtin_amdgcn_exp2f(x);
#else
  return __exp2f(x);
#endif
}
__device__ __forceinline__ float log2f_fast(float x) {
#if __has_builtin(__builtin_amdgcn_logf)
  return __builtin_amdgcn_logf(x);
#else
  return __log2f(x);
#endif
}

// pre-scaled log2-domain ssp: input a = log2e*x; returns log2(0.5*2^a+0.5)
// = ssp(x)/ln2. NO multiply inside (log2e folded into the MFMA weights).
__device__ __forceinline__ float ssp_l2p(float a) {
  return log2f_fast(fmaf(0.5f, exp2f_fast(a), 0.5f));
}
// natural-domain variant (epilogue only, few calls)
__device__ __forceinline__ float ssp_l2(float x) {
  return ssp_l2p(1.44269504f * x);
}

__device__ __forceinline__ f16x2 pk2(float a, float b) {
#if __has_builtin(__builtin_amdgcn_cvt_pkrtz)
  return __builtin_bit_cast(f16x2, __builtin_amdgcn_cvt_pkrtz(a, b));
#else
  f16x2 t;
  t.x = (_Float16)a;
  t.y = (_Float16)b;
  return t;
#endif
}

// rbf A-fragment for k-base kk*32+lq*8 via exact exp recurrence:
// a_j = -10*(x0-0.1j)^2; a_{j+1}-a_j = 2x0-0.2j-0.1 -> v*=r, r*=e^-0.2.
// Underflow -> exact 0 (values outside window are < 1e-19).
__device__ __forceinline__ f16x8 rbf8(float dd, int kk, int lq) {
  const float x0 = dd - 0.1f * (float)(kk * 32 + lq * 8);
  float v = exp2f_fast(-14.4269504f * x0 * x0);                // e^{a_0}
  float r = exp2f_fast(fmaf(2.88539008f, x0, -0.144269504f));  // e^{2x0-0.1}
  float w0 = v;
  v *= r; r *= 0.818730753f; float w1 = v;
  v *= r; r *= 0.818730753f; float w2 = v;
  v *= r; r *= 0.818730753f; float w3 = v;
  v *= r; r *= 0.818730753f; float w4 = v;
  v *= r; r *= 0.818730753f; float w5 = v;
  v *= r; r *= 0.818730753f; float w6 = v;
  v *= r;                    float w7 = v;
  union { f16x8 v8; f16x2 p[4]; } u;
  u.p[0] = pk2(w0, w1);
  u.p[1] = pk2(w2, w3);
  u.p[2] = pk2(w4, w5);
  u.p[3] = pk2(w6, w7);
  return u.v8;
}

// Pack log2e*W1 [300,128] -> f16 B-frag layout [10kk][8nt][64l][8j] at ws[0..40960)
// and W2 [128,128] -> [4kk][8nt][64l][8j] at ws[40960..57344).
__global__ void prep_pack(const float* __restrict__ W1, const float* __restrict__ W2,
                          unsigned short* __restrict__ ws) {
  int gid = blockIdx.x * 256 + threadIdx.x;
  if (gid < 40960) {
    int j = gid & 7, l = (gid >> 3) & 63, ntg = (gid >> 9) & 7, kk = gid >> 12;
    int k = kk * 32 + (l >> 4) * 8 + j;
    int h = ntg * 16 + (l & 15);
    float v = (k < 300) ? 1.44269504f * W1[k * 128 + h] : 0.f;
    ws[gid] = __builtin_bit_cast(unsigned short, (_Float16)v);
  } else if (gid < 57344) {
    int g2 = gid - 40960;
    int j = g2 & 7, l = (g2 >> 3) & 63, ntg = (g2 >> 9) & 7, kk = g2 >> 12;
    int k = kk * 32 + (l >> 4) * 8 + j;
    int h = ntg * 16 + (l & 15);
    ws[gid] = __builtin_bit_cast(unsigned short, (_Float16)W2[k * 128 + h]);
  }
}

__global__ __launch_bounds__(512, 4) void interaction_kernel(
    const float* __restrict__ nodef, const float* __restrict__ pos,
    const float* __restrict__ valid, const unsigned short* __restrict__ ws,
    const float* __restrict__ Wa1, const float* __restrict__ Wa2,
    const float* __restrict__ Wa3, float* __restrict__ out) {
  __shared__ __align__(16) _Float16 ytile[2][64 * 136];   // 34,816 B double-buffered
  __shared__ __align__(16) unsigned short W2pk[16384];    // 32,768 B
  __shared__ float d_lds[256];
  __shared__ int k0arr[256];
  __shared__ unsigned short jord[256];
  __shared__ unsigned short pr[2][256];
  __shared__ int kklo[16], kkhi[16];
  __shared__ float xrow[128], h1row[128], hhrow[128], a2row[128];
  __shared__ float partial[4][128];

  const int t = threadIdx.x;

  // ---- stage W2 fragments into LDS ONCE per block (amortized over 2 rows) ----
  {
    const uint4* src = (const uint4*)(ws + 40960);
    uint4* d2 = (uint4*)W2pk;
    for (int i = t; i < 2048; i += 512) d2[i] = src[i];
  }

  const int wid = t >> 6, l = t & 63;
  const int jg = wid >> 1, hgrp = wid & 1;  // wave tile: 16 j-rows x 64 h-cols
  const int lr = l & 15, lq = l >> 4;

  // ---- 2 rows per block: bid = blockIdx.x, blockIdx.x + 512 ----
  for (int rr = 0; rr < 2; ++rr) {
    const int bid = blockIdx.x + rr * 512;  // b*256 + i
    const int b = bid >> 8;

    __syncthreads();  // fences prior row's epilogue reads / W2pk stage

    if (t < 128) xrow[t] = nodef[bid * 128 + t];
    if (t < 256) {
      const float qx = pos[bid * 3 + 0], qy = pos[bid * 3 + 1], qz = pos[bid * 3 + 2];
      const float px = pos[(b * 256 + t) * 3 + 0];
      const float py = pos[(b * 256 + t) * 3 + 1];
      const float pz = pos[(b * 256 + t) * 3 + 2];
      const float dx = px - qx, dy = py - qy, dz = pz - qz;
      const float dd = sqrtf(dx * dx + dy * dy + dz * dz);
      d_lds[t] = dd;
      k0arr[t] = __float2int_rn(dd * 10.f);
    }
    __syncthreads();

    // ---- rank-sort, parallelized (proven): 512 threads x 128-entry scans ----
    {
      const int j = t & 255, half = t >> 8;
      const int key = k0arr[j];
      int rank = 0;
      const int base = half * 128;
      for (int j2 = base; j2 < base + 128; ++j2) {
        const int k2 = k0arr[j2];
        rank += (k2 < key || (k2 == key && j2 < j)) ? 1 : 0;
      }
      pr[half][j] = (unsigned short)rank;
    }
    // h1 = x @ Wa1 (partials over 4 thread-groups)
    {
      const int hh_ = t & 127, part = t >> 7;
      float a = 0.f;
#pragma unroll 8
      for (int k = part * 32; k < part * 32 + 32; ++k) a += xrow[k] * Wa1[k * 128 + hh_];
      partial[part][hh_] = a;
    }
    __syncthreads();
    if (t < 256) jord[pr[0][t] + pr[1][t]] = (unsigned short)t;
    if (t < 128)
      h1row[t] = partial[0][t] + partial[1][t] + partial[2][t] + partial[3][t];
    __syncthreads();
    // per sorted-16-group K-step ranges (window +-12: exp(-10*1.2^2)=5.6e-7)
    if (t < 16) {
      const int base = t * 16;
      const int klo = max(0, k0arr[jord[base]] - 12);
      const int khi = min(319, k0arr[jord[base + 15]] + 12);
      kklo[t] = klo >> 5;
      kkhi[t] = (khi >> 5) + 1;
    }
    __syncthreads();

    float sumv[4] = {0.f, 0.f, 0.f, 0.f};
    f32x4 acc[4];   // GEMM1 accumulators
    f32x4 acc2[4];  // GEMM2 accumulators

    // ---- main loop: 4 chunks of 64 sorted j's; ONE barrier per chunk ----
    for (int cc = 0; cc < 4; ++cc) {
      const int buf = cc & 1;
      const int g = cc * 4 + jg;
      const float dd = d_lds[jord[cc * 64 + jg * 16 + lr]];
      const int lo = kklo[g];
      const int n = kkhi[g] - lo;  // wave-uniform, 1..3

      // GEMM1: straight-line n in {1,2}; rare tail loop for n==3.
#pragma unroll
      for (int r = 0; r < 4; ++r) acc[r] = f32x4{0, 0, 0, 0};
      const unsigned short* pb = &ws[((lo * 8 + hgrp * 4) * 64 + l) * 8];
      const f16x8 c00 = *(const f16x8*)(pb + 0 * 512);
      const f16x8 c01 = *(const f16x8*)(pb + 1 * 512);
      const f16x8 c02 = *(const f16x8*)(pb + 2 * 512);
      const f16x8 c03 = *(const f16x8*)(pb + 3 * 512);
      f16x8 c10, c11, c12, c13;
      if (n > 1) {  // wave-uniform
        c10 = *(const f16x8*)(pb + 4096 + 0 * 512);
        c11 = *(const f16x8*)(pb + 4096 + 1 * 512);
        c12 = *(const f16x8*)(pb + 4096 + 2 * 512);
        c13 = *(const f16x8*)(pb + 4096 + 3 * 512);
      }
      {
        const f16x8 af0 = rbf8(dd, lo, lq);
        acc[0] = __builtin_amdgcn_mfma_f32_16x16x32_f16(af0, c00, acc[0], 0, 0, 0);
        acc[1] = __builtin_amdgcn_mfma_f32_16x16x32_f16(af0, c01, acc[1], 0, 0, 0);
        acc[2] = __builtin_amdgcn_mfma_f32_16x16x32_f16(af0, c02, acc[2], 0, 0, 0);
        acc[3] = __builtin_amdgcn_mfma_f32_16x16x32_f16(af0, c03, acc[3], 0, 0, 0);
      }
      if (n > 1) {
        const f16x8 af1 = rbf8(dd, lo + 1, lq);
        acc[0] = __builtin_amdgcn_mfma_f32_16x16x32_f16(af1, c10, acc[0], 0, 0, 0);
        acc[1] = __builtin_amdgcn_mfma_f32_16x16x32_f16(af1, c11, acc[1], 0, 0, 0);
        acc[2] = __builtin_amdgcn_mfma_f32_16x16x32_f16(af1, c12, acc[2], 0, 0, 0);
        acc[3] = __builtin_amdgcn_mfma_f32_16x16x32_f16(af1, c13, acc[3], 0, 0, 0);
      }
      for (int kk = lo + 2; kk < lo + n; ++kk) {  // rare (n==3)
        const unsigned short* p = pb + (kk - lo) * 4096;
        const f16x8 d0 = *(const f16x8*)(p + 0 * 512);
        const f16x8 d1 = *(const f16x8*)(p + 1 * 512);
        const f16x8 d2 = *(const f16x8*)(p + 2 * 512);
        const f16x8 d3 = *(const f16x8*)(p + 3 * 512);
        const f16x8 af = rbf8(dd, kk, lq);
        acc[0] = __builtin_amdgcn_mfma_f32_16x16x32_f16(af, d0, acc[0], 0, 0, 0);
        acc[1] = __builtin_amdgcn_mfma_f32_16x16x32_f16(af, d1, acc[1], 0, 0, 0);
        acc[2] = __builtin_amdgcn_mfma_f32_16x16x32_f16(af, d2, acc[2], 0, 0, 0);
        acc[3] = __builtin_amdgcn_mfma_f32_16x16x32_f16(af, d3, acc[3], 0, 0, 0);
      }
      // y' = ssp_l2p(acc) -> y tile (acc is log2e-scaled via W1pk; no mul)
#pragma unroll
      for (int nt = 0; nt < 4; ++nt)
#pragma unroll
        for (int r = 0; r < 4; ++r)
          ytile[buf][(jg * 16 + lq * 4 + r) * 136 + hgrp * 64 + nt * 16 + lr] =
              (_Float16)ssp_l2p(acc[nt][r]);
      __syncthreads();  // the ONLY barrier: orders this chunk's W before its R

      // GEMM2: acc2 = y' @ W2 (dense K=128) from LDS. y' = ssp/ln2, so
      // y' @ W2 = log2e*(ssp@W2): stays in log2 domain for the next ssp_l2p.
#pragma unroll
      for (int r = 0; r < 4; ++r) acc2[r] = f32x4{0, 0, 0, 0};
#pragma unroll
      for (int kk = 0; kk < 4; ++kk) {
        const f16x8 afr =
            *(const f16x8*)&ytile[buf][(jg * 16 + lr) * 136 + kk * 32 + lq * 8];
#pragma unroll
        for (int nt = 0; nt < 4; ++nt) {
          const f16x8 bfr = *(const f16x8*)&W2pk[((kk * 8 + hgrp * 4 + nt) * 64 + l) * 8];
          acc2[nt] = __builtin_amdgcn_mfma_f32_16x16x32_f16(afr, bfr, acc2[nt], 0, 0, 0);
        }
      }
      // accumulate sum_j in log2 domain (ln2 applied once in the reduction)
#pragma unroll
      for (int nt = 0; nt < 4; ++nt)
#pragma unroll
        for (int r = 0; r < 4; ++r) sumv[nt] += ssp_l2p(acc2[nt][r]);
      // no second barrier: next chunk writes the OTHER buffer (round-10 proof)
    }

    // ---- reduce sum_j partials (16 per h-column); f32 scratch over ytile[0].
    {
      float* red = (float*)&ytile[0][0];
#pragma unroll
      for (int nt = 0; nt < 4; ++nt)
        red[(jg * 4 + lq) * 128 + hgrp * 64 + nt * 16 + lr] = 0.69314718f * sumv[nt];
    }
    __syncthreads();
    if (t < 128) {
      const float* red = (const float*)&ytile[0][0];
      float s = 0.f;
#pragma unroll
      for (int q = 0; q < 16; ++q) s += red[q * 128 + t];
      hhrow[t] = h1row[t] * s;  // CFConv: h * sum_j filt
    }
    __syncthreads();
    // a2 = ssp(hh @ Wa2)
    {
      const int hh_ = t & 127, part = t >> 7;
      float a = 0.f;
#pragma unroll 8
      for (int k = part * 32; k < part * 32 + 32; ++k) a += hhrow[k] * Wa2[k * 128 + hh_];
      partial[part][hh_] = a;
    }
    __syncthreads();
    if (t < 128)
      a2row[t] = 0.69314718f *
                 ssp_l2(partial[0][t] + partial[1][t] + partial[2][t] + partial[3][t]);
    __syncthreads();
    // out = x + (a2 @ Wa3) * valid
    {
      const int hh_ = t & 127, part = t >> 7;
      float a = 0.f;
#pragma unroll 8
      for (int k = part * 32; k < part * 32 + 32; ++k) a += a2row[k] * Wa3[k * 128 + hh_];
      partial[part][hh_] = a;
    }
    __syncthreads();
    if (t < 128)
      out[bid * 128 + t] =
          xrow[t] +
          (partial[0][t] + partial[1][t] + partial[2][t] + partial[3][t]) * valid[bid];
  }
}

extern "C" void kernel_launch(void* const* d_in, const int* in_sizes, int n_in,
                              void* d_out, int out_size, void* d_ws, size_t ws_size,
                              hipStream_t stream) {
  const float* nodef = (const float*)d_in[0];
  const float* pos   = (const float*)d_in[1];
  const float* valid = (const float*)d_in[2];
  const float* W1    = (const float*)d_in[3];
  const float* W2    = (const float*)d_in[4];
  const float* Wa1   = (const float*)d_in[5];
  const float* Wa2   = (const float*)d_in[6];
  const float* Wa3   = (const float*)d_in[7];
  float* outp = (float*)d_out;
  unsigned short* wsp = (unsigned short*)d_ws;  // 57,344 f16 = 114,688 B

  prep_pack<<<224, 256, 0, stream>>>(W1, W2, wsp);
  interaction_kernel<<<512, 512, 0, stream>>>(nodef, pos, valid, wsp,
                                              Wa1, Wa2, Wa3, outp);
}

// Round 16
// 49.338 us; speedup vs baseline: 2.0593x; 2.0593x over previous
//
#include <hip/hip_runtime.h>

// InteractionLayer (SchNet-style) — MFMA f16. Round-14 proven kernel + epilogue
// load-batching. MI355X gfx950. B=4, N=256, NF=H=128, K=300, gamma=10, dk=0.1.
// Block = one (b,i) row: 1024 blocks x 512 threads (8 waves: jg 0..3 x hgrp 0..1).
// OCCUPANCY IS A HARD WALL [rounds 3/5/8/10 + m69 quantum]: footprint = 64 arch
// + 32 acc = 96 regs -> the 65..128 band -> 16 waves/CU; 24 waves would need
// <=64 TOTAL which forces catastrophic spill (round 4). Rounds 9/15: wrapping
// more state (acc[8] / outer row loop) makes the allocator spill at 64 instead
// of growing. So: 2-block/CU, latency-bound; optimize the per-wave path only.
//  - GEMM1: rbf[64j x 320k] @ (log2e*W1) f16 MFMA; rbf exact exp-recurrence in
//    regs; K-steps per sorted 16-row group (window +-12, n in {1,2,3});
//    straight-line n=1/2 + rare tail; B-frags direct from global (L2).
//  - ssp in log2 domain, log2e folded into W1pk: no per-element mul.
//  - GEMM2: y' @ W2 (LDS-staged); sum_j in log2 domain, ln2 applied once.
//  - main loop: 1 barrier/chunk via ytile double-buffer.
//  - NEW: epilogue GEMVs unroll 32 (was 8) -> all 32 Wa loads issue ahead of
//    the FMA chain (acc regs dead there; 4 latency waits -> 1 per GEMV).
//
// MFMA 16x16x32 layouts (gfx950):
//   A: lane l elem j -> A[l&15][(l>>4)*8 + j]
//   B: lane l elem j -> B[(l>>4)*8 + j][l&15]
//   D: lane l reg  r -> D[(l>>4)*4 + r][l&15]

typedef _Float16 f16x8 __attribute__((ext_vector_type(8)));
typedef _Float16 f16x2 __attribute__((ext_vector_type(2)));
typedef float f32x4 __attribute__((ext_vector_type(4)));

__device__ __forceinline__ float exp2f_fast(float x) {
#if __has_builtin(__builtin_amdgcn_exp2f)
  return __builtin_amdgcn_exp2f(x);
#else
  return __exp2f(x);
#endif
}
__device__ __forceinline__ float log2f_fast(float x) {
#if __has_builtin(__builtin_amdgcn_logf)
  return __builtin_amdgcn_logf(x);
#else
  return __log2f(x);
#endif
}

// pre-scaled log2-domain ssp: input a = log2e*x; returns log2(0.5*2^a+0.5)
// = ssp(x)/ln2. NO multiply inside (log2e folded into the MFMA weights).
__device__ __forceinline__ float ssp_l2p(float a) {
  return log2f_fast(fmaf(0.5f, exp2f_fast(a), 0.5f));
}
// natural-domain variant (epilogue only, few calls)
__device__ __forceinline__ float ssp_l2(float x) {
  return ssp_l2p(1.44269504f * x);
}

__device__ __forceinline__ f16x2 pk2(float a, float b) {
#if __has_builtin(__builtin_amdgcn_cvt_pkrtz)
  return __builtin_bit_cast(f16x2, __builtin_amdgcn_cvt_pkrtz(a, b));
#else
  f16x2 t;
  t.x = (_Float16)a;
  t.y = (_Float16)b;
  return t;
#endif
}

// rbf A-fragment for k-base kk*32+lq*8 via exact exp recurrence:
// a_j = -10*(x0-0.1j)^2; a_{j+1}-a_j = 2x0-0.2j-0.1 -> v*=r, r*=e^-0.2.
// Underflow -> exact 0 (values outside window are < 1e-19).
__device__ __forceinline__ f16x8 rbf8(float dd, int kk, int lq) {
  const float x0 = dd - 0.1f * (float)(kk * 32 + lq * 8);
  float v = exp2f_fast(-14.4269504f * x0 * x0);                // e^{a_0}
  float r = exp2f_fast(fmaf(2.88539008f, x0, -0.144269504f));  // e^{2x0-0.1}
  float w0 = v;
  v *= r; r *= 0.818730753f; float w1 = v;
  v *= r; r *= 0.818730753f; float w2 = v;
  v *= r; r *= 0.818730753f; float w3 = v;
  v *= r; r *= 0.818730753f; float w4 = v;
  v *= r; r *= 0.818730753f; float w5 = v;
  v *= r; r *= 0.818730753f; float w6 = v;
  v *= r;                    float w7 = v;
  union { f16x8 v8; f16x2 p[4]; } u;
  u.p[0] = pk2(w0, w1);
  u.p[1] = pk2(w2, w3);
  u.p[2] = pk2(w4, w5);
  u.p[3] = pk2(w6, w7);
  return u.v8;
}

// Pack log2e*W1 [300,128] -> f16 B-frag layout [10kk][8nt][64l][8j] at ws[0..40960)
// and W2 [128,128] -> [4kk][8nt][64l][8j] at ws[40960..57344).
__global__ void prep_pack(const float* __restrict__ W1, const float* __restrict__ W2,
                          unsigned short* __restrict__ ws) {
  int gid = blockIdx.x * 256 + threadIdx.x;
  if (gid < 40960) {
    int j = gid & 7, l = (gid >> 3) & 63, ntg = (gid >> 9) & 7, kk = gid >> 12;
    int k = kk * 32 + (l >> 4) * 8 + j;
    int h = ntg * 16 + (l & 15);
    float v = (k < 300) ? 1.44269504f * W1[k * 128 + h] : 0.f;
    ws[gid] = __builtin_bit_cast(unsigned short, (_Float16)v);
  } else if (gid < 57344) {
    int g2 = gid - 40960;
    int j = g2 & 7, l = (g2 >> 3) & 63, ntg = (g2 >> 9) & 7, kk = g2 >> 12;
    int k = kk * 32 + (l >> 4) * 8 + j;
    int h = ntg * 16 + (l & 15);
    ws[gid] = __builtin_bit_cast(unsigned short, (_Float16)W2[k * 128 + h]);
  }
}

__global__ __launch_bounds__(512, 4) void interaction_kernel(
    const float* __restrict__ nodef, const float* __restrict__ pos,
    const float* __restrict__ valid, const unsigned short* __restrict__ ws,
    const float* __restrict__ Wa1, const float* __restrict__ Wa2,
    const float* __restrict__ Wa3, float* __restrict__ out) {
  __shared__ __align__(16) _Float16 ytile[2][64 * 136];   // 34,816 B double-buffered
  __shared__ __align__(16) unsigned short W2pk[16384];    // 32,768 B
  __shared__ float d_lds[256];
  __shared__ int k0arr[256];
  __shared__ unsigned short jord[256];
  __shared__ unsigned short pr[2][256];
  __shared__ int kklo[16], kkhi[16];
  __shared__ float xrow[128], h1row[128], hhrow[128], a2row[128];
  __shared__ float partial[4][128];

  const int t = threadIdx.x;
  const int bid = blockIdx.x;  // b*256 + i
  const int b = bid >> 8;

  // ---- stage W2 fragments into LDS (16B coalesced) ----
  {
    const uint4* src = (const uint4*)(ws + 40960);
    uint4* d2 = (uint4*)W2pk;
    for (int i = t; i < 2048; i += 512) d2[i] = src[i];
  }
  if (t < 128) xrow[t] = nodef[bid * 128 + t];
  if (t < 256) {
    const float qx = pos[bid * 3 + 0], qy = pos[bid * 3 + 1], qz = pos[bid * 3 + 2];
    const float px = pos[(b * 256 + t) * 3 + 0];
    const float py = pos[(b * 256 + t) * 3 + 1];
    const float pz = pos[(b * 256 + t) * 3 + 2];
    const float dx = px - qx, dy = py - qy, dz = pz - qz;
    const float dd = sqrtf(dx * dx + dy * dy + dz * dz);
    d_lds[t] = dd;
    k0arr[t] = __float2int_rn(dd * 10.f);
  }
  __syncthreads();

  // ---- rank-sort, parallelized (proven round 9): 512 threads x 128 scans ----
  {
    const int j = t & 255, half = t >> 8;
    const int key = k0arr[j];
    int rank = 0;
    const int base = half * 128;
    for (int j2 = base; j2 < base + 128; ++j2) {
      const int k2 = k0arr[j2];
      rank += (k2 < key || (k2 == key && j2 < j)) ? 1 : 0;
    }
    pr[half][j] = (unsigned short)rank;
  }
  // h1 = x @ Wa1 (partials over 4 thread-groups; overlaps the sort)
  {
    const int hh_ = t & 127, part = t >> 7;
    float a = 0.f;
#pragma unroll 8
    for (int k = part * 32; k < part * 32 + 32; ++k) a += xrow[k] * Wa1[k * 128 + hh_];
    partial[part][hh_] = a;
  }
  __syncthreads();
  if (t < 256) jord[pr[0][t] + pr[1][t]] = (unsigned short)t;
  if (t < 128)
    h1row[t] = partial[0][t] + partial[1][t] + partial[2][t] + partial[3][t];
  __syncthreads();
  // per sorted-16-group K-step ranges (window +-12: exp(-10*1.2^2)=5.6e-7)
  if (t < 16) {
    const int base = t * 16;
    const int klo = max(0, k0arr[jord[base]] - 12);
    const int khi = min(319, k0arr[jord[base + 15]] + 12);
    kklo[t] = klo >> 5;
    kkhi[t] = (khi >> 5) + 1;
  }
  __syncthreads();

  const int wid = t >> 6, l = t & 63;
  const int jg = wid >> 1, hgrp = wid & 1;  // wave tile: 16 j-rows x 64 h-cols
  const int lr = l & 15, lq = l >> 4;
  float sumv[4] = {0.f, 0.f, 0.f, 0.f};
  f32x4 acc[4];   // GEMM1 accumulators
  f32x4 acc2[4];  // GEMM2 accumulators

  // ---- main loop: 4 chunks of 64 sorted j's; ONE barrier per chunk ----
  for (int cc = 0; cc < 4; ++cc) {
    const int buf = cc & 1;
    const int g = cc * 4 + jg;
    const float dd = d_lds[jord[cc * 64 + jg * 16 + lr]];
    const int lo = kklo[g];
    const int n = kkhi[g] - lo;  // wave-uniform, 1..3

    // GEMM1: straight-line for the common n in {1,2}; rare tail loop for n>2.
#pragma unroll
    for (int r = 0; r < 4; ++r) acc[r] = f32x4{0, 0, 0, 0};
    const unsigned short* pb = &ws[((lo * 8 + hgrp * 4) * 64 + l) * 8];
    const f16x8 c00 = *(const f16x8*)(pb + 0 * 512);
    const f16x8 c01 = *(const f16x8*)(pb + 1 * 512);
    const f16x8 c02 = *(const f16x8*)(pb + 2 * 512);
    const f16x8 c03 = *(const f16x8*)(pb + 3 * 512);
    f16x8 c10, c11, c12, c13;
    if (n > 1) {  // wave-uniform
      c10 = *(const f16x8*)(pb + 4096 + 0 * 512);
      c11 = *(const f16x8*)(pb + 4096 + 1 * 512);
      c12 = *(const f16x8*)(pb + 4096 + 2 * 512);
      c13 = *(const f16x8*)(pb + 4096 + 3 * 512);
    }
    {
      const f16x8 af0 = rbf8(dd, lo, lq);
      acc[0] = __builtin_amdgcn_mfma_f32_16x16x32_f16(af0, c00, acc[0], 0, 0, 0);
      acc[1] = __builtin_amdgcn_mfma_f32_16x16x32_f16(af0, c01, acc[1], 0, 0, 0);
      acc[2] = __builtin_amdgcn_mfma_f32_16x16x32_f16(af0, c02, acc[2], 0, 0, 0);
      acc[3] = __builtin_amdgcn_mfma_f32_16x16x32_f16(af0, c03, acc[3], 0, 0, 0);
    }
    if (n > 1) {
      const f16x8 af1 = rbf8(dd, lo + 1, lq);
      acc[0] = __builtin_amdgcn_mfma_f32_16x16x32_f16(af1, c10, acc[0], 0, 0, 0);
      acc[1] = __builtin_amdgcn_mfma_f32_16x16x32_f16(af1, c11, acc[1], 0, 0, 0);
      acc[2] = __builtin_amdgcn_mfma_f32_16x16x32_f16(af1, c12, acc[2], 0, 0, 0);
      acc[3] = __builtin_amdgcn_mfma_f32_16x16x32_f16(af1, c13, acc[3], 0, 0, 0);
    }
    for (int kk = lo + 2; kk < lo + n; ++kk) {  // rare (n==3)
      const unsigned short* p = pb + (kk - lo) * 4096;
      const f16x8 d0 = *(const f16x8*)(p + 0 * 512);
      const f16x8 d1 = *(const f16x8*)(p + 1 * 512);
      const f16x8 d2 = *(const f16x8*)(p + 2 * 512);
      const f16x8 d3 = *(const f16x8*)(p + 3 * 512);
      const f16x8 af = rbf8(dd, kk, lq);
      acc[0] = __builtin_amdgcn_mfma_f32_16x16x32_f16(af, d0, acc[0], 0, 0, 0);
      acc[1] = __builtin_amdgcn_mfma_f32_16x16x32_f16(af, d1, acc[1], 0, 0, 0);
      acc[2] = __builtin_amdgcn_mfma_f32_16x16x32_f16(af, d2, acc[2], 0, 0, 0);
      acc[3] = __builtin_amdgcn_mfma_f32_16x16x32_f16(af, d3, acc[3], 0, 0, 0);
    }
    // y' = ssp_l2p(acc) -> y tile (acc is log2e-scaled via W1pk; no mul)
#pragma unroll
    for (int nt = 0; nt < 4; ++nt)
#pragma unroll
      for (int r = 0; r < 4; ++r)
        ytile[buf][(jg * 16 + lq * 4 + r) * 136 + hgrp * 64 + nt * 16 + lr] =
            (_Float16)ssp_l2p(acc[nt][r]);
    __syncthreads();  // the ONLY barrier: orders this chunk's W before its R

    // GEMM2: acc2 = y' @ W2 (dense K=128) from LDS. y' = ssp/ln2, so
    // y' @ W2 = log2e*(ssp@W2): stays in log2 domain for the next ssp_l2p.
#pragma unroll
    for (int r = 0; r < 4; ++r) acc2[r] = f32x4{0, 0, 0, 0};
#pragma unroll
    for (int kk = 0; kk < 4; ++kk) {
      const f16x8 afr =
          *(const f16x8*)&ytile[buf][(jg * 16 + lr) * 136 + kk * 32 + lq * 8];
#pragma unroll
      for (int nt = 0; nt < 4; ++nt) {
        const f16x8 bfr = *(const f16x8*)&W2pk[((kk * 8 + hgrp * 4 + nt) * 64 + l) * 8];
        acc2[nt] = __builtin_amdgcn_mfma_f32_16x16x32_f16(afr, bfr, acc2[nt], 0, 0, 0);
      }
    }
    // accumulate sum_j in log2 domain (ln2 applied once in the reduction)
#pragma unroll
    for (int nt = 0; nt < 4; ++nt)
#pragma unroll
      for (int r = 0; r < 4; ++r) sumv[nt] += ssp_l2p(acc2[nt][r]);
    // no second barrier: next chunk writes the OTHER buffer (round-10 proof)
  }

  // ---- reduce sum_j partials (16 per h-column); f32 scratch over ytile[0].
  {
    float* red = (float*)&ytile[0][0];
#pragma unroll
    for (int nt = 0; nt < 4; ++nt)
      red[(jg * 4 + lq) * 128 + hgrp * 64 + nt * 16 + lr] = 0.69314718f * sumv[nt];
  }
  __syncthreads();
  if (t < 128) {
    const float* red = (const float*)&ytile[0][0];
    float s = 0.f;
#pragma unroll
    for (int q = 0; q < 16; ++q) s += red[q * 128 + t];
    hhrow[t] = h1row[t] * s;  // CFConv: h * sum_j filt
  }
  __syncthreads();
  // a2 = ssp(hh @ Wa2) — unroll 32: all loads hoist ahead of the FMA chain
  {
    const int hh_ = t & 127, part = t >> 7;
    float a = 0.f;
#pragma unroll 32
    for (int k = part * 32; k < part * 32 + 32; ++k) a += hhrow[k] * Wa2[k * 128 + hh_];
    partial[part][hh_] = a;
  }
  __syncthreads();
  if (t < 128)
    a2row[t] = 0.69314718f *
               ssp_l2(partial[0][t] + partial[1][t] + partial[2][t] + partial[3][t]);
  __syncthreads();
  // out = x + (a2 @ Wa3) * valid — unroll 32
  {
    const int hh_ = t & 127, part = t >> 7;
    float a = 0.f;
#pragma unroll 32
    for (int k = part * 32; k < part * 32 + 32; ++k) a += a2row[k] * Wa3[k * 128 + hh_];
    partial[part][hh_] = a;
  }
  __syncthreads();
  if (t < 128)
    out[bid * 128 + t] =
        xrow[t] + (partial[0][t] + partial[1][t] + partial[2][t] + partial[3][t]) * valid[bid];
}

extern "C" void kernel_launch(void* const* d_in, const int* in_sizes, int n_in,
                              void* d_out, int out_size, void* d_ws, size_t ws_size,
                              hipStream_t stream) {
  const float* nodef = (const float*)d_in[0];
  const float* pos   = (const float*)d_in[1];
  const float* valid = (const float*)d_in[2];
  const float* W1    = (const float*)d_in[3];
  const float* W2    = (const float*)d_in[4];
  const float* Wa1   = (const float*)d_in[5];
  const float* Wa2   = (const float*)d_in[6];
  const float* Wa3   = (const float*)d_in[7];
  float* outp = (float*)d_out;
  unsigned short* wsp = (unsigned short*)d_ws;  // 57,344 f16 = 114,688 B

  prep_pack<<<224, 256, 0, stream>>>(W1, W2, wsp);
  interaction_kernel<<<1024, 512, 0, stream>>>(nodef, pos, valid, wsp,
                                               Wa1, Wa2, Wa3, outp);
}

// Round 17
// 46.893 us; speedup vs baseline: 2.1666x; 1.0521x over previous
//
#include <hip/hip_runtime.h>

// InteractionLayer (SchNet-style) — MFMA f16, barrier-free main loop v2. gfx950.
// B=4, N=256, NF=H=128, K=300, gamma=10, dk=0.1.
// Block = one (b,i) row: 1024 blocks x 512 threads (8 waves).
// STRUCTURE (round-9 wave-private + round-14 register discipline):
//   Each wave owns 16 sorted j-rows x ALL 128 h; 256 j's in 2 outer iters.
//   ytile rows are wave-private -> GEMM1-write / GEMM2-read ordered by in-wave
//   lgkmcnt: ZERO barriers in the main loop; no inter-wave n-imbalance waits
//   (each wave runs its own K-window length). hgrp is a SEQUENTIAL inner pass
//   reusing ONE acc[4] (round-9's acc[8] spilled; rounds 6/9/15: never exceed
//   the acc[4] budget). rbf recomputed per hg pass (2 cheap trans/kk).
//   Reduction scratch reuses ytile with a pre-write barrier (separate red[]
//   would exceed the 80 KB 2-block/CU LDS budget).
// Proven components kept: parallel rank-sort; window +-12 (n in {1,2,3});
//   straight-line n=1/2 GEMM1 + rare tail; B-frags direct from global;
//   log2e folded into W1pk (ssp with no per-element mul); W2pk LDS-staged;
//   sum_j in log2 domain (ln2 once); epilogue GEMVs unroll 32 (round 16, ~3us).
// [tripwire: FETCH > 20 MB => spill => revert to round-16 kernel]
//
// MFMA 16x16x32 layouts (gfx950):
//   A: lane l elem j -> A[l&15][(l>>4)*8 + j]
//   B: lane l elem j -> B[(l>>4)*8 + j][l&15]
//   D: lane l reg  r -> D[(l>>4)*4 + r][l&15]

typedef _Float16 f16x8 __attribute__((ext_vector_type(8)));
typedef _Float16 f16x2 __attribute__((ext_vector_type(2)));
typedef float f32x4 __attribute__((ext_vector_type(4)));

__device__ __forceinline__ float exp2f_fast(float x) {
#if __has_builtin(__builtin_amdgcn_exp2f)
  return __builtin_amdgcn_exp2f(x);
#else
  return __exp2f(x);
#endif
}
__device__ __forceinline__ float log2f_fast(float x) {
#if __has_builtin(__builtin_amdgcn_logf)
  return __builtin_amdgcn_logf(x);
#else
  return __log2f(x);
#endif
}

// pre-scaled log2-domain ssp: input a = log2e*x; returns log2(0.5*2^a+0.5)
// = ssp(x)/ln2. NO multiply inside (log2e folded into the MFMA weights).
__device__ __forceinline__ float ssp_l2p(float a) {
  return log2f_fast(fmaf(0.5f, exp2f_fast(a), 0.5f));
}
// natural-domain variant (epilogue only, few calls)
__device__ __forceinline__ float ssp_l2(float x) {
  return ssp_l2p(1.44269504f * x);
}

__device__ __forceinline__ f16x2 pk2(float a, float b) {
#if __has_builtin(__builtin_amdgcn_cvt_pkrtz)
  return __builtin_bit_cast(f16x2, __builtin_amdgcn_cvt_pkrtz(a, b));
#else
  f16x2 t;
  t.x = (_Float16)a;
  t.y = (_Float16)b;
  return t;
#endif
}

// rbf A-fragment for k-base kk*32+lq*8 via exact exp recurrence:
// a_j = -10*(x0-0.1j)^2; a_{j+1}-a_j = 2x0-0.2j-0.1 -> v*=r, r*=e^-0.2.
// Underflow -> exact 0 (values outside window are < 1e-19).
__device__ __forceinline__ f16x8 rbf8(float dd, int kk, int lq) {
  const float x0 = dd - 0.1f * (float)(kk * 32 + lq * 8);
  float v = exp2f_fast(-14.4269504f * x0 * x0);                // e^{a_0}
  float r = exp2f_fast(fmaf(2.88539008f, x0, -0.144269504f));  // e^{2x0-0.1}
  float w0 = v;
  v *= r; r *= 0.818730753f; float w1 = v;
  v *= r; r *= 0.818730753f; float w2 = v;
  v *= r; r *= 0.818730753f; float w3 = v;
  v *= r; r *= 0.818730753f; float w4 = v;
  v *= r; r *= 0.818730753f; float w5 = v;
  v *= r; r *= 0.818730753f; float w6 = v;
  v *= r;                    float w7 = v;
  union { f16x8 v8; f16x2 p[4]; } u;
  u.p[0] = pk2(w0, w1);
  u.p[1] = pk2(w2, w3);
  u.p[2] = pk2(w4, w5);
  u.p[3] = pk2(w6, w7);
  return u.v8;
}

// Pack log2e*W1 [300,128] -> f16 B-frag layout [10kk][8nt][64l][8j] at ws[0..40960)
// and W2 [128,128] -> [4kk][8nt][64l][8j] at ws[40960..57344).
__global__ void prep_pack(const float* __restrict__ W1, const float* __restrict__ W2,
                          unsigned short* __restrict__ ws) {
  int gid = blockIdx.x * 256 + threadIdx.x;
  if (gid < 40960) {
    int j = gid & 7, l = (gid >> 3) & 63, ntg = (gid >> 9) & 7, kk = gid >> 12;
    int k = kk * 32 + (l >> 4) * 8 + j;
    int h = ntg * 16 + (l & 15);
    float v = (k < 300) ? 1.44269504f * W1[k * 128 + h] : 0.f;
    ws[gid] = __builtin_bit_cast(unsigned short, (_Float16)v);
  } else if (gid < 57344) {
    int g2 = gid - 40960;
    int j = g2 & 7, l = (g2 >> 3) & 63, ntg = (g2 >> 9) & 7, kk = g2 >> 12;
    int k = kk * 32 + (l >> 4) * 8 + j;
    int h = ntg * 16 + (l & 15);
    ws[gid] = __builtin_bit_cast(unsigned short, (_Float16)W2[k * 128 + h]);
  }
}

__global__ __launch_bounds__(512, 4) void interaction_kernel(
    const float* __restrict__ nodef, const float* __restrict__ pos,
    const float* __restrict__ valid, const unsigned short* __restrict__ ws,
    const float* __restrict__ Wa1, const float* __restrict__ Wa2,
    const float* __restrict__ Wa3, float* __restrict__ out) {
  __shared__ __align__(16) _Float16 ytile[128 * 136];     // 34,816 B; wave-private rows
  __shared__ __align__(16) unsigned short W2pk[16384];    // 32,768 B
  __shared__ float d_lds[256];
  __shared__ int k0arr[256];
  __shared__ unsigned short jord[256];
  __shared__ unsigned short pr[2][256];
  __shared__ int kklo[16], kkhi[16];
  __shared__ float xrow[128], h1row[128], hhrow[128], a2row[128];
  __shared__ float partial[4][128];

  const int t = threadIdx.x;
  const int bid = blockIdx.x;  // b*256 + i
  const int b = bid >> 8;

  // ---- stage W2 fragments into LDS (16B coalesced) ----
  {
    const uint4* src = (const uint4*)(ws + 40960);
    uint4* d2 = (uint4*)W2pk;
    for (int i = t; i < 2048; i += 512) d2[i] = src[i];
  }
  if (t < 128) xrow[t] = nodef[bid * 128 + t];
  if (t < 256) {
    const float qx = pos[bid * 3 + 0], qy = pos[bid * 3 + 1], qz = pos[bid * 3 + 2];
    const float px = pos[(b * 256 + t) * 3 + 0];
    const float py = pos[(b * 256 + t) * 3 + 1];
    const float pz = pos[(b * 256 + t) * 3 + 2];
    const float dx = px - qx, dy = py - qy, dz = pz - qz;
    const float dd = sqrtf(dx * dx + dy * dy + dz * dz);
    d_lds[t] = dd;
    k0arr[t] = __float2int_rn(dd * 10.f);
  }
  __syncthreads();

  // ---- rank-sort, parallelized (proven round 9): 512 threads x 128 scans ----
  {
    const int j = t & 255, half = t >> 8;
    const int key = k0arr[j];
    int rank = 0;
    const int base = half * 128;
    for (int j2 = base; j2 < base + 128; ++j2) {
      const int k2 = k0arr[j2];
      rank += (k2 < key || (k2 == key && j2 < j)) ? 1 : 0;
    }
    pr[half][j] = (unsigned short)rank;
  }
  // h1 = x @ Wa1 (partials over 4 thread-groups; overlaps the sort)
  {
    const int hh_ = t & 127, part = t >> 7;
    float a = 0.f;
#pragma unroll 8
    for (int k = part * 32; k < part * 32 + 32; ++k) a += xrow[k] * Wa1[k * 128 + hh_];
    partial[part][hh_] = a;
  }
  __syncthreads();
  if (t < 256) jord[pr[0][t] + pr[1][t]] = (unsigned short)t;
  if (t < 128)
    h1row[t] = partial[0][t] + partial[1][t] + partial[2][t] + partial[3][t];
  __syncthreads();
  // per sorted-16-group K-step ranges (window +-12: exp(-10*1.2^2)=5.6e-7)
  if (t < 16) {
    const int base = t * 16;
    const int klo = max(0, k0arr[jord[base]] - 12);
    const int khi = min(319, k0arr[jord[base + 15]] + 12);
    kklo[t] = klo >> 5;
    kkhi[t] = (khi >> 5) + 1;
  }
  __syncthreads();

  const int w = t >> 6, l = t & 63;
  const int lr = l & 15, lq = l >> 4;
  float sumv[8];
#pragma unroll
  for (int r = 0; r < 8; ++r) sumv[r] = 0.f;
  f32x4 acc[4];  // ONE accumulator set, reused by every GEMM pass (reg-lean)

  // ---- main loop: 2 outer iters x (wave-private 16 rows x 128 h). NO BARRIERS.
  for (int it = 0; it < 2; ++it) {
    const int g = it * 8 + w;  // this wave's sorted 16-row group
    const float dd = d_lds[jord[it * 128 + w * 16 + lr]];
    const int lo = kklo[g];
    const int n = kkhi[g] - lo;  // wave-uniform, 1..3

    // GEMM1: two sequential hg passes (h-halves), acc[4] reused; straight-line
    // n in {1,2}; rare tail loop for n==3. rbf recomputed per pass (cheap).
#pragma unroll
    for (int hg = 0; hg < 2; ++hg) {
#pragma unroll
      for (int r = 0; r < 4; ++r) acc[r] = f32x4{0, 0, 0, 0};
      const unsigned short* pb = &ws[((lo * 8 + hg * 4) * 64 + l) * 8];
      const f16x8 c00 = *(const f16x8*)(pb + 0 * 512);
      const f16x8 c01 = *(const f16x8*)(pb + 1 * 512);
      const f16x8 c02 = *(const f16x8*)(pb + 2 * 512);
      const f16x8 c03 = *(const f16x8*)(pb + 3 * 512);
      f16x8 c10, c11, c12, c13;
      if (n > 1) {  // wave-uniform
        c10 = *(const f16x8*)(pb + 4096 + 0 * 512);
        c11 = *(const f16x8*)(pb + 4096 + 1 * 512);
        c12 = *(const f16x8*)(pb + 4096 + 2 * 512);
        c13 = *(const f16x8*)(pb + 4096 + 3 * 512);
      }
      {
        const f16x8 af0 = rbf8(dd, lo, lq);
        acc[0] = __builtin_amdgcn_mfma_f32_16x16x32_f16(af0, c00, acc[0], 0, 0, 0);
        acc[1] = __builtin_amdgcn_mfma_f32_16x16x32_f16(af0, c01, acc[1], 0, 0, 0);
        acc[2] = __builtin_amdgcn_mfma_f32_16x16x32_f16(af0, c02, acc[2], 0, 0, 0);
        acc[3] = __builtin_amdgcn_mfma_f32_16x16x32_f16(af0, c03, acc[3], 0, 0, 0);
      }
      if (n > 1) {
        const f16x8 af1 = rbf8(dd, lo + 1, lq);
        acc[0] = __builtin_amdgcn_mfma_f32_16x16x32_f16(af1, c10, acc[0], 0, 0, 0);
        acc[1] = __builtin_amdgcn_mfma_f32_16x16x32_f16(af1, c11, acc[1], 0, 0, 0);
        acc[2] = __builtin_amdgcn_mfma_f32_16x16x32_f16(af1, c12, acc[2], 0, 0, 0);
        acc[3] = __builtin_amdgcn_mfma_f32_16x16x32_f16(af1, c13, acc[3], 0, 0, 0);
      }
      for (int kk = lo + 2; kk < lo + n; ++kk) {  // rare (n==3)
        const unsigned short* p = pb + (kk - lo) * 4096;
        const f16x8 d0 = *(const f16x8*)(p + 0 * 512);
        const f16x8 d1 = *(const f16x8*)(p + 1 * 512);
        const f16x8 d2 = *(const f16x8*)(p + 2 * 512);
        const f16x8 d3 = *(const f16x8*)(p + 3 * 512);
        const f16x8 af = rbf8(dd, kk, lq);
        acc[0] = __builtin_amdgcn_mfma_f32_16x16x32_f16(af, d0, acc[0], 0, 0, 0);
        acc[1] = __builtin_amdgcn_mfma_f32_16x16x32_f16(af, d1, acc[1], 0, 0, 0);
        acc[2] = __builtin_amdgcn_mfma_f32_16x16x32_f16(af, d2, acc[2], 0, 0, 0);
        acc[3] = __builtin_amdgcn_mfma_f32_16x16x32_f16(af, d3, acc[3], 0, 0, 0);
      }
      // y' = ssp_l2p(acc) -> wave-private ytile rows (in-wave order; no barrier)
#pragma unroll
      for (int nt = 0; nt < 4; ++nt)
#pragma unroll
        for (int r = 0; r < 4; ++r)
          ytile[(w * 16 + lq * 4 + r) * 136 + hg * 64 + nt * 16 + lr] =
              (_Float16)ssp_l2p(acc[nt][r]);
    }

    // GEMM2: two sequential hg2 passes, acc[4] reused; A-frags from OWN rows
    // (lgkmcnt orders the prior ds_writes; no barrier).
#pragma unroll
    for (int hg2 = 0; hg2 < 2; ++hg2) {
#pragma unroll
      for (int r = 0; r < 4; ++r) acc[r] = f32x4{0, 0, 0, 0};
#pragma unroll
      for (int kk = 0; kk < 4; ++kk) {
        const f16x8 afr =
            *(const f16x8*)&ytile[(w * 16 + lr) * 136 + kk * 32 + lq * 8];
#pragma unroll
        for (int nt = 0; nt < 4; ++nt) {
          const f16x8 bfr =
              *(const f16x8*)&W2pk[((kk * 8 + hg2 * 4 + nt) * 64 + l) * 8];
          acc[nt] = __builtin_amdgcn_mfma_f32_16x16x32_f16(afr, bfr, acc[nt], 0, 0, 0);
        }
      }
      // accumulate sum_j in log2 domain (ln2 applied once in the reduction)
#pragma unroll
      for (int nt = 0; nt < 4; ++nt)
#pragma unroll
        for (int r = 0; r < 4; ++r) sumv[hg2 * 4 + nt] += ssp_l2p(acc[nt][r]);
    }
  }

  // ---- reduce sum_j partials: 8 waves x 4 lq = 32 per h-column.
  // Reuse ytile as f32 scratch: barrier BEFORE writes (other waves may still
  // be reading their private rows), barrier after.
  __syncthreads();
  {
    float* red = (float*)&ytile[0];
#pragma unroll
    for (int q = 0; q < 8; ++q) {
      const int hg2 = q >> 2, nt = q & 3;
      red[(w * 4 + lq) * 128 + hg2 * 64 + nt * 16 + lr] = 0.69314718f * sumv[q];
    }
  }
  __syncthreads();
  if (t < 128) {
    const float* red = (const float*)&ytile[0];
    float s = 0.f;
#pragma unroll
    for (int q = 0; q < 32; ++q) s += red[q * 128 + t];
    hhrow[t] = h1row[t] * s;  // CFConv: h * sum_j filt
  }
  __syncthreads();
  // a2 = ssp(hh @ Wa2) — unroll 32: all loads hoist ahead of the FMA chain
  {
    const int hh_ = t & 127, part = t >> 7;
    float a = 0.f;
#pragma unroll 32
    for (int k = part * 32; k < part * 32 + 32; ++k) a += hhrow[k] * Wa2[k * 128 + hh_];
    partial[part][hh_] = a;
  }
  __syncthreads();
  if (t < 128)
    a2row[t] = 0.69314718f *
               ssp_l2(partial[0][t] + partial[1][t] + partial[2][t] + partial[3][t]);
  __syncthreads();
  // out = x + (a2 @ Wa3) * valid — unroll 32
  {
    const int hh_ = t & 127, part = t >> 7;
    float a = 0.f;
#pragma unroll 32
    for (int k = part * 32; k < part * 32 + 32; ++k) a += a2row[k] * Wa3[k * 128 + hh_];
    partial[part][hh_] = a;
  }
  __syncthreads();
  if (t < 128)
    out[bid * 128 + t] =
        xrow[t] + (partial[0][t] + partial[1][t] + partial[2][t] + partial[3][t]) * valid[bid];
}

extern "C" void kernel_launch(void* const* d_in, const int* in_sizes, int n_in,
                              void* d_out, int out_size, void* d_ws, size_t ws_size,
                              hipStream_t stream) {
  const float* nodef = (const float*)d_in[0];
  const float* pos   = (const float*)d_in[1];
  const float* valid = (const float*)d_in[2];
  const float* W1    = (const float*)d_in[3];
  const float* W2    = (const float*)d_in[4];
  const float* Wa1   = (const float*)d_in[5];
  const float* Wa2   = (const float*)d_in[6];
  const float* Wa3   = (const float*)d_in[7];
  float* outp = (float*)d_out;
  unsigned short* wsp = (unsigned short*)d_ws;  // 57,344 f16 = 114,688 B

  prep_pack<<<224, 256, 0, stream>>>(W1, W2, wsp);
  interaction_kernel<<<1024, 512, 0, stream>>>(nodef, pos, valid, wsp,
                                               Wa1, Wa2, Wa3, outp);
}

// Round 18
// 46.291 us; speedup vs baseline: 2.1948x; 1.0130x over previous
//
#include <hip/hip_runtime.h>

// InteractionLayer (SchNet-style) — MFMA f16, barrier-free main loop v2 +
// vectorized sort scan + tree reduction. MI355X gfx950.
// B=4, N=256, NF=H=128, K=300, gamma=10, dk=0.1.
// Block = one (b,i) row: 1024 blocks x 512 threads (8 waves).
// STRUCTURE (proven round 17, 44.8us kernel):
//   Each wave owns 16 sorted j-rows x ALL 128 h; 2 outer iters; ytile rows
//   wave-private -> ZERO main-loop barriers; hgrp sequential with ONE acc[4]
//   (the proven register budget; acc[8]/outer-loop variants spill).
// Round-18 deltas (arithmetic in journal):
//   1. sort scan reads k0arr as int4: 32 ds_read_b128 vs 128 ds_read_b32
//      (~742 -> ~384 LDS-pipe cyc/wave; same comparisons, deterministic).
//   2. sum_j reduction 2-stage tree: 512 thr x 8 + 128 thr x 4 (was 128 x 32).
// Proven components: window +-12 (n in {1,2,3}); straight-line n=1/2 GEMM1;
//   W1 B-frags direct from global; log2e folded into W1pk (mul-free ssp);
//   W2pk LDS-staged; sum_j in log2 domain; epilogue GEMVs unroll 32.
// [tripwire: FETCH > 20 MB => spill => revert]
//
// MFMA 16x16x32 layouts (gfx950):
//   A: lane l elem j -> A[l&15][(l>>4)*8 + j]
//   B: lane l elem j -> B[(l>>4)*8 + j][l&15]
//   D: lane l reg  r -> D[(l>>4)*4 + r][l&15]

typedef _Float16 f16x8 __attribute__((ext_vector_type(8)));
typedef _Float16 f16x2 __attribute__((ext_vector_type(2)));
typedef float f32x4 __attribute__((ext_vector_type(4)));

__device__ __forceinline__ float exp2f_fast(float x) {
#if __has_builtin(__builtin_amdgcn_exp2f)
  return __builtin_amdgcn_exp2f(x);
#else
  return __exp2f(x);
#endif
}
__device__ __forceinline__ float log2f_fast(float x) {
#if __has_builtin(__builtin_amdgcn_logf)
  return __builtin_amdgcn_logf(x);
#else
  return __log2f(x);
#endif
}

// pre-scaled log2-domain ssp: input a = log2e*x; returns log2(0.5*2^a+0.5)
// = ssp(x)/ln2. NO multiply inside (log2e folded into the MFMA weights).
__device__ __forceinline__ float ssp_l2p(float a) {
  return log2f_fast(fmaf(0.5f, exp2f_fast(a), 0.5f));
}
// natural-domain variant (epilogue only, few calls)
__device__ __forceinline__ float ssp_l2(float x) {
  return ssp_l2p(1.44269504f * x);
}

__device__ __forceinline__ f16x2 pk2(float a, float b) {
#if __has_builtin(__builtin_amdgcn_cvt_pkrtz)
  return __builtin_bit_cast(f16x2, __builtin_amdgcn_cvt_pkrtz(a, b));
#else
  f16x2 t;
  t.x = (_Float16)a;
  t.y = (_Float16)b;
  return t;
#endif
}

// rbf A-fragment for k-base kk*32+lq*8 via exact exp recurrence:
// a_j = -10*(x0-0.1j)^2; a_{j+1}-a_j = 2x0-0.2j-0.1 -> v*=r, r*=e^-0.2.
// Underflow -> exact 0 (values outside window are < 1e-19).
__device__ __forceinline__ f16x8 rbf8(float dd, int kk, int lq) {
  const float x0 = dd - 0.1f * (float)(kk * 32 + lq * 8);
  float v = exp2f_fast(-14.4269504f * x0 * x0);                // e^{a_0}
  float r = exp2f_fast(fmaf(2.88539008f, x0, -0.144269504f));  // e^{2x0-0.1}
  float w0 = v;
  v *= r; r *= 0.818730753f; float w1 = v;
  v *= r; r *= 0.818730753f; float w2 = v;
  v *= r; r *= 0.818730753f; float w3 = v;
  v *= r; r *= 0.818730753f; float w4 = v;
  v *= r; r *= 0.818730753f; float w5 = v;
  v *= r; r *= 0.818730753f; float w6 = v;
  v *= r;                    float w7 = v;
  union { f16x8 v8; f16x2 p[4]; } u;
  u.p[0] = pk2(w0, w1);
  u.p[1] = pk2(w2, w3);
  u.p[2] = pk2(w4, w5);
  u.p[3] = pk2(w6, w7);
  return u.v8;
}

// Pack log2e*W1 [300,128] -> f16 B-frag layout [10kk][8nt][64l][8j] at ws[0..40960)
// and W2 [128,128] -> [4kk][8nt][64l][8j] at ws[40960..57344).
__global__ void prep_pack(const float* __restrict__ W1, const float* __restrict__ W2,
                          unsigned short* __restrict__ ws) {
  int gid = blockIdx.x * 256 + threadIdx.x;
  if (gid < 40960) {
    int j = gid & 7, l = (gid >> 3) & 63, ntg = (gid >> 9) & 7, kk = gid >> 12;
    int k = kk * 32 + (l >> 4) * 8 + j;
    int h = ntg * 16 + (l & 15);
    float v = (k < 300) ? 1.44269504f * W1[k * 128 + h] : 0.f;
    ws[gid] = __builtin_bit_cast(unsigned short, (_Float16)v);
  } else if (gid < 57344) {
    int g2 = gid - 40960;
    int j = g2 & 7, l = (g2 >> 3) & 63, ntg = (g2 >> 9) & 7, kk = g2 >> 12;
    int k = kk * 32 + (l >> 4) * 8 + j;
    int h = ntg * 16 + (l & 15);
    ws[gid] = __builtin_bit_cast(unsigned short, (_Float16)W2[k * 128 + h]);
  }
}

__global__ __launch_bounds__(512, 4) void interaction_kernel(
    const float* __restrict__ nodef, const float* __restrict__ pos,
    const float* __restrict__ valid, const unsigned short* __restrict__ ws,
    const float* __restrict__ Wa1, const float* __restrict__ Wa2,
    const float* __restrict__ Wa3, float* __restrict__ out) {
  __shared__ __align__(16) _Float16 ytile[128 * 136];     // 34,816 B; wave-private rows
  __shared__ __align__(16) unsigned short W2pk[16384];    // 32,768 B
  __shared__ float d_lds[256];
  __shared__ __align__(16) int k0arr[256];
  __shared__ unsigned short jord[256];
  __shared__ unsigned short pr[2][256];
  __shared__ int kklo[16], kkhi[16];
  __shared__ float xrow[128], h1row[128], hhrow[128], a2row[128];
  __shared__ float partial[4][128];

  const int t = threadIdx.x;
  const int bid = blockIdx.x;  // b*256 + i
  const int b = bid >> 8;

  // ---- stage W2 fragments into LDS (16B coalesced) ----
  {
    const uint4* src = (const uint4*)(ws + 40960);
    uint4* d2 = (uint4*)W2pk;
    for (int i = t; i < 2048; i += 512) d2[i] = src[i];
  }
  if (t < 128) xrow[t] = nodef[bid * 128 + t];
  if (t < 256) {
    const float qx = pos[bid * 3 + 0], qy = pos[bid * 3 + 1], qz = pos[bid * 3 + 2];
    const float px = pos[(b * 256 + t) * 3 + 0];
    const float py = pos[(b * 256 + t) * 3 + 1];
    const float pz = pos[(b * 256 + t) * 3 + 2];
    const float dx = px - qx, dy = py - qy, dz = pz - qz;
    const float dd = sqrtf(dx * dx + dy * dy + dz * dz);
    d_lds[t] = dd;
    k0arr[t] = __float2int_rn(dd * 10.f);
  }
  __syncthreads();

  // ---- rank-sort, vectorized: 512 threads, each scans 128 entries as 32
  //      int4 broadcast reads (identical comparisons -> identical jord) ----
  {
    const int j = t & 255, half = t >> 8;
    const int key = k0arr[j];
    int rank = 0;
    const int4* kv = (const int4*)k0arr;
    const int mbase = half * 32, jbase = half * 128;
#pragma unroll 8
    for (int m = 0; m < 32; ++m) {
      const int4 v4 = kv[mbase + m];
      const int j2 = jbase + m * 4;
      rank += (v4.x < key || (v4.x == key && j2 + 0 < j)) ? 1 : 0;
      rank += (v4.y < key || (v4.y == key && j2 + 1 < j)) ? 1 : 0;
      rank += (v4.z < key || (v4.z == key && j2 + 2 < j)) ? 1 : 0;
      rank += (v4.w < key || (v4.w == key && j2 + 3 < j)) ? 1 : 0;
    }
    pr[half][j] = (unsigned short)rank;
  }
  // h1 = x @ Wa1 (partials over 4 thread-groups; overlaps the sort)
  {
    const int hh_ = t & 127, part = t >> 7;
    float a = 0.f;
#pragma unroll 8
    for (int k = part * 32; k < part * 32 + 32; ++k) a += xrow[k] * Wa1[k * 128 + hh_];
    partial[part][hh_] = a;
  }
  __syncthreads();
  if (t < 256) jord[pr[0][t] + pr[1][t]] = (unsigned short)t;
  if (t < 128)
    h1row[t] = partial[0][t] + partial[1][t] + partial[2][t] + partial[3][t];
  __syncthreads();
  // per sorted-16-group K-step ranges (window +-12: exp(-10*1.2^2)=5.6e-7)
  if (t < 16) {
    const int base = t * 16;
    const int klo = max(0, k0arr[jord[base]] - 12);
    const int khi = min(319, k0arr[jord[base + 15]] + 12);
    kklo[t] = klo >> 5;
    kkhi[t] = (khi >> 5) + 1;
  }
  __syncthreads();

  const int w = t >> 6, l = t & 63;
  const int lr = l & 15, lq = l >> 4;
  float sumv[8];
#pragma unroll
  for (int r = 0; r < 8; ++r) sumv[r] = 0.f;
  f32x4 acc[4];  // ONE accumulator set, reused by every GEMM pass (reg-lean)

  // ---- main loop: 2 outer iters x (wave-private 16 rows x 128 h). NO BARRIERS.
  for (int it = 0; it < 2; ++it) {
    const int g = it * 8 + w;  // this wave's sorted 16-row group
    const float dd = d_lds[jord[it * 128 + w * 16 + lr]];
    const int lo = kklo[g];
    const int n = kkhi[g] - lo;  // wave-uniform, 1..3

    // GEMM1: two sequential hg passes (h-halves), acc[4] reused; straight-line
    // n in {1,2}; rare tail loop for n==3. rbf recomputed per pass (cheap).
#pragma unroll
    for (int hg = 0; hg < 2; ++hg) {
#pragma unroll
      for (int r = 0; r < 4; ++r) acc[r] = f32x4{0, 0, 0, 0};
      const unsigned short* pb = &ws[((lo * 8 + hg * 4) * 64 + l) * 8];
      const f16x8 c00 = *(const f16x8*)(pb + 0 * 512);
      const f16x8 c01 = *(const f16x8*)(pb + 1 * 512);
      const f16x8 c02 = *(const f16x8*)(pb + 2 * 512);
      const f16x8 c03 = *(const f16x8*)(pb + 3 * 512);
      f16x8 c10, c11, c12, c13;
      if (n > 1) {  // wave-uniform
        c10 = *(const f16x8*)(pb + 4096 + 0 * 512);
        c11 = *(const f16x8*)(pb + 4096 + 1 * 512);
        c12 = *(const f16x8*)(pb + 4096 + 2 * 512);
        c13 = *(const f16x8*)(pb + 4096 + 3 * 512);
      }
      {
        const f16x8 af0 = rbf8(dd, lo, lq);
        acc[0] = __builtin_amdgcn_mfma_f32_16x16x32_f16(af0, c00, acc[0], 0, 0, 0);
        acc[1] = __builtin_amdgcn_mfma_f32_16x16x32_f16(af0, c01, acc[1], 0, 0, 0);
        acc[2] = __builtin_amdgcn_mfma_f32_16x16x32_f16(af0, c02, acc[2], 0, 0, 0);
        acc[3] = __builtin_amdgcn_mfma_f32_16x16x32_f16(af0, c03, acc[3], 0, 0, 0);
      }
      if (n > 1) {
        const f16x8 af1 = rbf8(dd, lo + 1, lq);
        acc[0] = __builtin_amdgcn_mfma_f32_16x16x32_f16(af1, c10, acc[0], 0, 0, 0);
        acc[1] = __builtin_amdgcn_mfma_f32_16x16x32_f16(af1, c11, acc[1], 0, 0, 0);
        acc[2] = __builtin_amdgcn_mfma_f32_16x16x32_f16(af1, c12, acc[2], 0, 0, 0);
        acc[3] = __builtin_amdgcn_mfma_f32_16x16x32_f16(af1, c13, acc[3], 0, 0, 0);
      }
      for (int kk = lo + 2; kk < lo + n; ++kk) {  // rare (n==3)
        const unsigned short* p = pb + (kk - lo) * 4096;
        const f16x8 d0 = *(const f16x8*)(p + 0 * 512);
        const f16x8 d1 = *(const f16x8*)(p + 1 * 512);
        const f16x8 d2 = *(const f16x8*)(p + 2 * 512);
        const f16x8 d3 = *(const f16x8*)(p + 3 * 512);
        const f16x8 af = rbf8(dd, kk, lq);
        acc[0] = __builtin_amdgcn_mfma_f32_16x16x32_f16(af, d0, acc[0], 0, 0, 0);
        acc[1] = __builtin_amdgcn_mfma_f32_16x16x32_f16(af, d1, acc[1], 0, 0, 0);
        acc[2] = __builtin_amdgcn_mfma_f32_16x16x32_f16(af, d2, acc[2], 0, 0, 0);
        acc[3] = __builtin_amdgcn_mfma_f32_16x16x32_f16(af, d3, acc[3], 0, 0, 0);
      }
      // y' = ssp_l2p(acc) -> wave-private ytile rows (in-wave order; no barrier)
#pragma unroll
      for (int nt = 0; nt < 4; ++nt)
#pragma unroll
        for (int r = 0; r < 4; ++r)
          ytile[(w * 16 + lq * 4 + r) * 136 + hg * 64 + nt * 16 + lr] =
              (_Float16)ssp_l2p(acc[nt][r]);
    }

    // GEMM2: two sequential hg2 passes, acc[4] reused; A-frags from OWN rows
    // (lgkmcnt orders the prior ds_writes; no barrier).
#pragma unroll
    for (int hg2 = 0; hg2 < 2; ++hg2) {
#pragma unroll
      for (int r = 0; r < 4; ++r) acc[r] = f32x4{0, 0, 0, 0};
#pragma unroll
      for (int kk = 0; kk < 4; ++kk) {
        const f16x8 afr =
            *(const f16x8*)&ytile[(w * 16 + lr) * 136 + kk * 32 + lq * 8];
#pragma unroll
        for (int nt = 0; nt < 4; ++nt) {
          const f16x8 bfr =
              *(const f16x8*)&W2pk[((kk * 8 + hg2 * 4 + nt) * 64 + l) * 8];
          acc[nt] = __builtin_amdgcn_mfma_f32_16x16x32_f16(afr, bfr, acc[nt], 0, 0, 0);
        }
      }
      // accumulate sum_j in log2 domain (ln2 applied once in the reduction)
#pragma unroll
      for (int nt = 0; nt < 4; ++nt)
#pragma unroll
        for (int r = 0; r < 4; ++r) sumv[hg2 * 4 + nt] += ssp_l2p(acc[nt][r]);
    }
  }

  // ---- reduce sum_j partials: 8 waves x 4 lq = 32 rows per h-column.
  // Reuse ytile as f32 scratch; 2-stage tree (512 x 8 + 128 x 4).
  __syncthreads();
  {
    float* red = (float*)&ytile[0];
#pragma unroll
    for (int q = 0; q < 8; ++q) {
      const int hg2 = q >> 2, nt = q & 3;
      red[(w * 4 + lq) * 128 + hg2 * 64 + nt * 16 + lr] = 0.69314718f * sumv[q];
    }
  }
  __syncthreads();
  {
    const float* red = (const float*)&ytile[0];
    const int hh_ = t & 127, seg = t >> 7;  // seg 0..3 sums rows seg*8..seg*8+7
    float s = 0.f;
#pragma unroll
    for (int q = seg * 8; q < seg * 8 + 8; ++q) s += red[q * 128 + hh_];
    partial[seg][hh_] = s;
  }
  __syncthreads();
  if (t < 128) {
    const float s = partial[0][t] + partial[1][t] + partial[2][t] + partial[3][t];
    hhrow[t] = h1row[t] * s;  // CFConv: h * sum_j filt
  }
  __syncthreads();
  // a2 = ssp(hh @ Wa2) — unroll 32: all loads hoist ahead of the FMA chain
  {
    const int hh_ = t & 127, part = t >> 7;
    float a = 0.f;
#pragma unroll 32
    for (int k = part * 32; k < part * 32 + 32; ++k) a += hhrow[k] * Wa2[k * 128 + hh_];
    partial[part][hh_] = a;
  }
  __syncthreads();
  if (t < 128)
    a2row[t] = 0.69314718f *
               ssp_l2(partial[0][t] + partial[1][t] + partial[2][t] + partial[3][t]);
  __syncthreads();
  // out = x + (a2 @ Wa3) * valid — unroll 32
  {
    const int hh_ = t & 127, part = t >> 7;
    float a = 0.f;
#pragma unroll 32
    for (int k = part * 32; k < part * 32 + 32; ++k) a += a2row[k] * Wa3[k * 128 + hh_];
    partial[part][hh_] = a;
  }
  __syncthreads();
  if (t < 128)
    out[bid * 128 + t] =
        xrow[t] + (partial[0][t] + partial[1][t] + partial[2][t] + partial[3][t]) * valid[bid];
}

extern "C" void kernel_launch(void* const* d_in, const int* in_sizes, int n_in,
                              void* d_out, int out_size, void* d_ws, size_t ws_size,
                              hipStream_t stream) {
  const float* nodef = (const float*)d_in[0];
  const float* pos   = (const float*)d_in[1];
  const float* valid = (const float*)d_in[2];
  const float* W1    = (const float*)d_in[3];
  const float* W2    = (const float*)d_in[4];
  const float* Wa1   = (const float*)d_in[5];
  const float* Wa2   = (const float*)d_in[6];
  const float* Wa3   = (const float*)d_in[7];
  float* outp = (float*)d_out;
  unsigned short* wsp = (unsigned short*)d_ws;  // 57,344 f16 = 114,688 B

  prep_pack<<<224, 256, 0, stream>>>(W1, W2, wsp);
  interaction_kernel<<<1024, 512, 0, stream>>>(nodef, pos, valid, wsp,
                                               Wa1, Wa2, Wa3, outp);
}

// Round 19
// 44.583 us; speedup vs baseline: 2.2789x; 1.0383x over previous
//
#include <hip/hip_runtime.h>

// InteractionLayer (SchNet-style) — MFMA f16, barrier-free main loop v2 +
// polynomial ssp + hoisted rbf fragments. MI355X gfx950.
// B=4, N=256, NF=H=128, K=300, gamma=10, dk=0.1.
// Block = one (b,i) row: 1024 blocks x 512 threads (8 waves).
// STRUCTURE (proven rounds 17/18, 44.4us kernel):
//   Each wave owns 16 sorted j-rows x ALL 128 h; 2 outer iters; ytile rows
//   wave-private -> ZERO main-loop barriers; hgrp sequential with ONE acc[4].
// Round-19 deltas (VALU/trans-chain cuts; range-justified):
//   1. POLY ssp in the main loop: log2(0.5*2^a+0.5) = a/2 + E(a^2), E even;
//      cubic fit at u={1,4,9}: err <= ~3e-4 for |a|<=3.5 (GEMM1 |a|<=3.6 by
//      |rbf.W1| bound; GEMM2 |a|<=2.2). 5 FMA replaces exp2+fma+log2 (2 trans).
//      Epilogue keeps exact ssp (2 calls/thread). [tripwire: absmax>0.05 => revert]
//   2. rbf A-frags af0/af1 computed once per iter, reused by both hg passes
//      (+8 regs, peak ~104 < 128 band; n==3 tail keeps recompute).
//      [tripwire: FETCH > 20 MB => spill => revert]
// Proven components: vectorized rank-sort (int4); window +-12 (n in {1,2,3});
//   straight-line n=1/2 GEMM1; W1 B-frags direct from global; log2e folded
//   into W1pk; W2pk LDS-staged; sum_j in log2 domain (ln2 once); 2-stage tree
//   reduction; epilogue GEMVs unroll 32.
//
// MFMA 16x16x32 layouts (gfx950):
//   A: lane l elem j -> A[l&15][(l>>4)*8 + j]
//   B: lane l elem j -> B[(l>>4)*8 + j][l&15]
//   D: lane l reg  r -> D[(l>>4)*4 + r][l&15]

typedef _Float16 f16x8 __attribute__((ext_vector_type(8)));
typedef _Float16 f16x2 __attribute__((ext_vector_type(2)));
typedef float f32x4 __attribute__((ext_vector_type(4)));

__device__ __forceinline__ float exp2f_fast(float x) {
#if __has_builtin(__builtin_amdgcn_exp2f)
  return __builtin_amdgcn_exp2f(x);
#else
  return __exp2f(x);
#endif
}
__device__ __forceinline__ float log2f_fast(float x) {
#if __has_builtin(__builtin_amdgcn_logf)
  return __builtin_amdgcn_logf(x);
#else
  return __log2f(x);
#endif
}

// POLY pre-scaled log2-domain ssp: a = log2e*x; returns log2(0.5*2^a+0.5)
// = a/2 + E(a^2), E(u) = u*(c1 + u*(c2 + u*c3)) fit at u={1,4,9}.
// err <= ~3e-4 for |a| <= 3.5 (exact at a=0; even+odd structure exact).
__device__ __forceinline__ float ssp_poly(float a) {
  const float u = a * a;
  const float E =
      u * fmaf(u, fmaf(u, 3.553873e-5f, -1.6711860e-3f), 8.6598148e-2f);
  return fmaf(a, 0.5f, E);
}
// exact natural-domain variant (epilogue only, 2 calls/thread)
__device__ __forceinline__ float ssp_l2(float x) {
  const float a = 1.44269504f * x;
  return log2f_fast(fmaf(0.5f, exp2f_fast(a), 0.5f));
}

__device__ __forceinline__ f16x2 pk2(float a, float b) {
#if __has_builtin(__builtin_amdgcn_cvt_pkrtz)
  return __builtin_bit_cast(f16x2, __builtin_amdgcn_cvt_pkrtz(a, b));
#else
  f16x2 t;
  t.x = (_Float16)a;
  t.y = (_Float16)b;
  return t;
#endif
}

// rbf A-fragment for k-base kk*32+lq*8 via exact exp recurrence:
// a_j = -10*(x0-0.1j)^2; a_{j+1}-a_j = 2x0-0.2j-0.1 -> v*=r, r*=e^-0.2.
// Underflow -> exact 0 (values outside window are < 1e-19).
__device__ __forceinline__ f16x8 rbf8(float dd, int kk, int lq) {
  const float x0 = dd - 0.1f * (float)(kk * 32 + lq * 8);
  float v = exp2f_fast(-14.4269504f * x0 * x0);                // e^{a_0}
  float r = exp2f_fast(fmaf(2.88539008f, x0, -0.144269504f));  // e^{2x0-0.1}
  float w0 = v;
  v *= r; r *= 0.818730753f; float w1 = v;
  v *= r; r *= 0.818730753f; float w2 = v;
  v *= r; r *= 0.818730753f; float w3 = v;
  v *= r; r *= 0.818730753f; float w4 = v;
  v *= r; r *= 0.818730753f; float w5 = v;
  v *= r; r *= 0.818730753f; float w6 = v;
  v *= r;                    float w7 = v;
  union { f16x8 v8; f16x2 p[4]; } u;
  u.p[0] = pk2(w0, w1);
  u.p[1] = pk2(w2, w3);
  u.p[2] = pk2(w4, w5);
  u.p[3] = pk2(w6, w7);
  return u.v8;
}

// Pack log2e*W1 [300,128] -> f16 B-frag layout [10kk][8nt][64l][8j] at ws[0..40960)
// and W2 [128,128] -> [4kk][8nt][64l][8j] at ws[40960..57344).
__global__ void prep_pack(const float* __restrict__ W1, const float* __restrict__ W2,
                          unsigned short* __restrict__ ws) {
  int gid = blockIdx.x * 256 + threadIdx.x;
  if (gid < 40960) {
    int j = gid & 7, l = (gid >> 3) & 63, ntg = (gid >> 9) & 7, kk = gid >> 12;
    int k = kk * 32 + (l >> 4) * 8 + j;
    int h = ntg * 16 + (l & 15);
    float v = (k < 300) ? 1.44269504f * W1[k * 128 + h] : 0.f;
    ws[gid] = __builtin_bit_cast(unsigned short, (_Float16)v);
  } else if (gid < 57344) {
    int g2 = gid - 40960;
    int j = g2 & 7, l = (g2 >> 3) & 63, ntg = (g2 >> 9) & 7, kk = g2 >> 12;
    int k = kk * 32 + (l >> 4) * 8 + j;
    int h = ntg * 16 + (l & 15);
    ws[gid] = __builtin_bit_cast(unsigned short, (_Float16)W2[k * 128 + h]);
  }
}

__global__ __launch_bounds__(512, 4) void interaction_kernel(
    const float* __restrict__ nodef, const float* __restrict__ pos,
    const float* __restrict__ valid, const unsigned short* __restrict__ ws,
    const float* __restrict__ Wa1, const float* __restrict__ Wa2,
    const float* __restrict__ Wa3, float* __restrict__ out) {
  __shared__ __align__(16) _Float16 ytile[128 * 136];     // 34,816 B; wave-private rows
  __shared__ __align__(16) unsigned short W2pk[16384];    // 32,768 B
  __shared__ float d_lds[256];
  __shared__ __align__(16) int k0arr[256];
  __shared__ unsigned short jord[256];
  __shared__ unsigned short pr[2][256];
  __shared__ int kklo[16], kkhi[16];
  __shared__ float xrow[128], h1row[128], hhrow[128], a2row[128];
  __shared__ float partial[4][128];

  const int t = threadIdx.x;
  const int bid = blockIdx.x;  // b*256 + i
  const int b = bid >> 8;

  // ---- stage W2 fragments into LDS (16B coalesced) ----
  {
    const uint4* src = (const uint4*)(ws + 40960);
    uint4* d2 = (uint4*)W2pk;
    for (int i = t; i < 2048; i += 512) d2[i] = src[i];
  }
  if (t < 128) xrow[t] = nodef[bid * 128 + t];
  if (t < 256) {
    const float qx = pos[bid * 3 + 0], qy = pos[bid * 3 + 1], qz = pos[bid * 3 + 2];
    const float px = pos[(b * 256 + t) * 3 + 0];
    const float py = pos[(b * 256 + t) * 3 + 1];
    const float pz = pos[(b * 256 + t) * 3 + 2];
    const float dx = px - qx, dy = py - qy, dz = pz - qz;
    const float dd = sqrtf(dx * dx + dy * dy + dz * dz);
    d_lds[t] = dd;
    k0arr[t] = __float2int_rn(dd * 10.f);
  }
  __syncthreads();

  // ---- rank-sort, vectorized: 512 threads, each scans 128 entries as 32
  //      int4 broadcast reads (identical comparisons -> identical jord) ----
  {
    const int j = t & 255, half = t >> 8;
    const int key = k0arr[j];
    int rank = 0;
    const int4* kv = (const int4*)k0arr;
    const int mbase = half * 32, jbase = half * 128;
#pragma unroll 8
    for (int m = 0; m < 32; ++m) {
      const int4 v4 = kv[mbase + m];
      const int j2 = jbase + m * 4;
      rank += (v4.x < key || (v4.x == key && j2 + 0 < j)) ? 1 : 0;
      rank += (v4.y < key || (v4.y == key && j2 + 1 < j)) ? 1 : 0;
      rank += (v4.z < key || (v4.z == key && j2 + 2 < j)) ? 1 : 0;
      rank += (v4.w < key || (v4.w == key && j2 + 3 < j)) ? 1 : 0;
    }
    pr[half][j] = (unsigned short)rank;
  }
  // h1 = x @ Wa1 (partials over 4 thread-groups; overlaps the sort)
  {
    const int hh_ = t & 127, part = t >> 7;
    float a = 0.f;
#pragma unroll 8
    for (int k = part * 32; k < part * 32 + 32; ++k) a += xrow[k] * Wa1[k * 128 + hh_];
    partial[part][hh_] = a;
  }
  __syncthreads();
  if (t < 256) jord[pr[0][t] + pr[1][t]] = (unsigned short)t;
  if (t < 128)
    h1row[t] = partial[0][t] + partial[1][t] + partial[2][t] + partial[3][t];
  __syncthreads();
  // per sorted-16-group K-step ranges (window +-12: exp(-10*1.2^2)=5.6e-7)
  if (t < 16) {
    const int base = t * 16;
    const int klo = max(0, k0arr[jord[base]] - 12);
    const int khi = min(319, k0arr[jord[base + 15]] + 12);
    kklo[t] = klo >> 5;
    kkhi[t] = (khi >> 5) + 1;
  }
  __syncthreads();

  const int w = t >> 6, l = t & 63;
  const int lr = l & 15, lq = l >> 4;
  float sumv[8];
#pragma unroll
  for (int r = 0; r < 8; ++r) sumv[r] = 0.f;
  f32x4 acc[4];  // ONE accumulator set, reused by every GEMM pass (reg-lean)

  // ---- main loop: 2 outer iters x (wave-private 16 rows x 128 h). NO BARRIERS.
  for (int it = 0; it < 2; ++it) {
    const int g = it * 8 + w;  // this wave's sorted 16-row group
    const float dd = d_lds[jord[it * 128 + w * 16 + lr]];
    const int lo = kklo[g];
    const int n = kkhi[g] - lo;  // wave-uniform, 1..3

    // rbf A-frags computed ONCE per iter (round-19: reused by both hg passes)
    const f16x8 af0 = rbf8(dd, lo, lq);
    f16x8 af1;
    if (n > 1) af1 = rbf8(dd, lo + 1, lq);

    // GEMM1: two sequential hg passes (h-halves), acc[4] reused; straight-line
    // n in {1,2}; rare tail loop for n==3 (rbf recomputed there only).
#pragma unroll
    for (int hg = 0; hg < 2; ++hg) {
#pragma unroll
      for (int r = 0; r < 4; ++r) acc[r] = f32x4{0, 0, 0, 0};
      const unsigned short* pb = &ws[((lo * 8 + hg * 4) * 64 + l) * 8];
      const f16x8 c00 = *(const f16x8*)(pb + 0 * 512);
      const f16x8 c01 = *(const f16x8*)(pb + 1 * 512);
      const f16x8 c02 = *(const f16x8*)(pb + 2 * 512);
      const f16x8 c03 = *(const f16x8*)(pb + 3 * 512);
      f16x8 c10, c11, c12, c13;
      if (n > 1) {  // wave-uniform
        c10 = *(const f16x8*)(pb + 4096 + 0 * 512);
        c11 = *(const f16x8*)(pb + 4096 + 1 * 512);
        c12 = *(const f16x8*)(pb + 4096 + 2 * 512);
        c13 = *(const f16x8*)(pb + 4096 + 3 * 512);
      }
      acc[0] = __builtin_amdgcn_mfma_f32_16x16x32_f16(af0, c00, acc[0], 0, 0, 0);
      acc[1] = __builtin_amdgcn_mfma_f32_16x16x32_f16(af0, c01, acc[1], 0, 0, 0);
      acc[2] = __builtin_amdgcn_mfma_f32_16x16x32_f16(af0, c02, acc[2], 0, 0, 0);
      acc[3] = __builtin_amdgcn_mfma_f32_16x16x32_f16(af0, c03, acc[3], 0, 0, 0);
      if (n > 1) {
        acc[0] = __builtin_amdgcn_mfma_f32_16x16x32_f16(af1, c10, acc[0], 0, 0, 0);
        acc[1] = __builtin_amdgcn_mfma_f32_16x16x32_f16(af1, c11, acc[1], 0, 0, 0);
        acc[2] = __builtin_amdgcn_mfma_f32_16x16x32_f16(af1, c12, acc[2], 0, 0, 0);
        acc[3] = __builtin_amdgcn_mfma_f32_16x16x32_f16(af1, c13, acc[3], 0, 0, 0);
      }
      for (int kk = lo + 2; kk < lo + n; ++kk) {  // rare (n==3)
        const unsigned short* p = pb + (kk - lo) * 4096;
        const f16x8 d0 = *(const f16x8*)(p + 0 * 512);
        const f16x8 d1 = *(const f16x8*)(p + 1 * 512);
        const f16x8 d2 = *(const f16x8*)(p + 2 * 512);
        const f16x8 d3 = *(const f16x8*)(p + 3 * 512);
        const f16x8 af = rbf8(dd, kk, lq);
        acc[0] = __builtin_amdgcn_mfma_f32_16x16x32_f16(af, d0, acc[0], 0, 0, 0);
        acc[1] = __builtin_amdgcn_mfma_f32_16x16x32_f16(af, d1, acc[1], 0, 0, 0);
        acc[2] = __builtin_amdgcn_mfma_f32_16x16x32_f16(af, d2, acc[2], 0, 0, 0);
        acc[3] = __builtin_amdgcn_mfma_f32_16x16x32_f16(af, d3, acc[3], 0, 0, 0);
      }
      // y' = ssp_poly(acc) -> wave-private ytile rows (in-wave order; no barrier)
#pragma unroll
      for (int nt = 0; nt < 4; ++nt)
#pragma unroll
        for (int r = 0; r < 4; ++r)
          ytile[(w * 16 + lq * 4 + r) * 136 + hg * 64 + nt * 16 + lr] =
              (_Float16)ssp_poly(acc[nt][r]);
    }

    // GEMM2: two sequential hg2 passes, acc[4] reused; A-frags from OWN rows
    // (lgkmcnt orders the prior ds_writes; no barrier).
#pragma unroll
    for (int hg2 = 0; hg2 < 2; ++hg2) {
#pragma unroll
      for (int r = 0; r < 4; ++r) acc[r] = f32x4{0, 0, 0, 0};
#pragma unroll
      for (int kk = 0; kk < 4; ++kk) {
        const f16x8 afr =
            *(const f16x8*)&ytile[(w * 16 + lr) * 136 + kk * 32 + lq * 8];
#pragma unroll
        for (int nt = 0; nt < 4; ++nt) {
          const f16x8 bfr =
              *(const f16x8*)&W2pk[((kk * 8 + hg2 * 4 + nt) * 64 + l) * 8];
          acc[nt] = __builtin_amdgcn_mfma_f32_16x16x32_f16(afr, bfr, acc[nt], 0, 0, 0);
        }
      }
      // accumulate sum_j in log2 domain (ln2 applied once in the reduction)
#pragma unroll
      for (int nt = 0; nt < 4; ++nt)
#pragma unroll
        for (int r = 0; r < 4; ++r) sumv[hg2 * 4 + nt] += ssp_poly(acc[nt][r]);
    }
  }

  // ---- reduce sum_j partials: 8 waves x 4 lq = 32 rows per h-column.
  // Reuse ytile as f32 scratch; 2-stage tree (512 x 8 + 128 x 4).
  __syncthreads();
  {
    float* red = (float*)&ytile[0];
#pragma unroll
    for (int q = 0; q < 8; ++q) {
      const int hg2 = q >> 2, nt = q & 3;
      red[(w * 4 + lq) * 128 + hg2 * 64 + nt * 16 + lr] = 0.69314718f * sumv[q];
    }
  }
  __syncthreads();
  {
    const float* red = (const float*)&ytile[0];
    const int hh_ = t & 127, seg = t >> 7;  // seg 0..3 sums rows seg*8..seg*8+7
    float s = 0.f;
#pragma unroll
    for (int q = seg * 8; q < seg * 8 + 8; ++q) s += red[q * 128 + hh_];
    partial[seg][hh_] = s;
  }
  __syncthreads();
  if (t < 128) {
    const float s = partial[0][t] + partial[1][t] + partial[2][t] + partial[3][t];
    hhrow[t] = h1row[t] * s;  // CFConv: h * sum_j filt
  }
  __syncthreads();
  // a2 = ssp(hh @ Wa2) — unroll 32: all loads hoist ahead of the FMA chain
  {
    const int hh_ = t & 127, part = t >> 7;
    float a = 0.f;
#pragma unroll 32
    for (int k = part * 32; k < part * 32 + 32; ++k) a += hhrow[k] * Wa2[k * 128 + hh_];
    partial[part][hh_] = a;
  }
  __syncthreads();
  if (t < 128)
    a2row[t] = 0.69314718f *
               ssp_l2(partial[0][t] + partial[1][t] + partial[2][t] + partial[3][t]);
  __syncthreads();
  // out = x + (a2 @ Wa3) * valid — unroll 32
  {
    const int hh_ = t & 127, part = t >> 7;
    float a = 0.f;
#pragma unroll 32
    for (int k = part * 32; k < part * 32 + 32; ++k) a += a2row[k] * Wa3[k * 128 + hh_];
    partial[part][hh_] = a;
  }
  __syncthreads();
  if (t < 128)
    out[bid * 128 + t] =
        xrow[t] + (partial[0][t] + partial[1][t] + partial[2][t] + partial[3][t]) * valid[bid];
}

extern "C" void kernel_launch(void* const* d_in, const int* in_sizes, int n_in,
                              void* d_out, int out_size, void* d_ws, size_t ws_size,
                              hipStream_t stream) {
  const float* nodef = (const float*)d_in[0];
  const float* pos   = (const float*)d_in[1];
  const float* valid = (const float*)d_in[2];
  const float* W1    = (const float*)d_in[3];
  const float* W2    = (const float*)d_in[4];
  const float* Wa1   = (const float*)d_in[5];
  const float* Wa2   = (const float*)d_in[6];
  const float* Wa3   = (const float*)d_in[7];
  float* outp = (float*)d_out;
  unsigned short* wsp = (unsigned short*)d_ws;  // 57,344 f16 = 114,688 B

  prep_pack<<<224, 256, 0, stream>>>(W1, W2, wsp);
  interaction_kernel<<<1024, 512, 0, stream>>>(nodef, pos, valid, wsp,
                                               Wa1, Wa2, Wa3, outp);
}

// Round 20
// 43.830 us; speedup vs baseline: 2.3181x; 1.0172x over previous
//
#include <hip/hip_runtime.h>

// InteractionLayer (SchNet-style) — MFMA f16, barrier-free main loop v2 +
// poly ssp + final small-lever bundle. MI355X gfx950.
// B=4, N=256, NF=H=128, K=300, gamma=10, dk=0.1.
// Block = one (b,i) row: 1024 blocks x 512 threads (8 waves).
// STRUCTURE (proven r17-r19, 43.1us kernel): each wave owns 16 sorted j-rows x
// ALL 128 h; 2 outer iters; ytile rows wave-private -> ZERO main-loop barriers;
// hg sequential with ONE acc[4] (the proven register budget).
// Round-20 deltas:
//  1. window +-12 -> +-10 (edge rbf e^-10=4.5e-5; omitted-term err ~7e-5 << 
//     0.0156 measured absmax): more n=1 groups -> ~15% fewer GEMM1 MFMAs/loads.
//  2. manual hg unroll with loads-before-rbf: hg0 B-frag loads issue before the
//     rbf recurrence (flight hidden); hg1 loads issue before hg0's poly-write.
//  3. prep_pack vectorized: 1 thread per 8-j fragment row, uint4 writes,
//     64B-segment reads (28 blocks vs 224 with 4B scatter).
// [tripwires: FETCH > 20 MB => spill => revert; absmax > 0.05 => revert window]
// Proven components: vectorized int4 rank-sort; straight-line n=1/2 GEMM1 +
//   rare n>=3 tail; W1 B-frags direct from global; log2e folded into W1pk;
//   poly ssp (a/2 + E(a^2), err<=3e-4 for |a|<=3.5); W2pk LDS-staged; sum_j in
//   log2 domain (ln2 once); 2-stage tree reduction; epilogue GEMVs unroll 32.
//
// MFMA 16x16x32 layouts (gfx950):
//   A: lane l elem j -> A[l&15][(l>>4)*8 + j]
//   B: lane l elem j -> B[(l>>4)*8 + j][l&15]
//   D: lane l reg  r -> D[(l>>4)*4 + r][l&15]

typedef _Float16 f16x8 __attribute__((ext_vector_type(8)));
typedef _Float16 f16x2 __attribute__((ext_vector_type(2)));
typedef float f32x4 __attribute__((ext_vector_type(4)));

__device__ __forceinline__ float exp2f_fast(float x) {
#if __has_builtin(__builtin_amdgcn_exp2f)
  return __builtin_amdgcn_exp2f(x);
#else
  return __exp2f(x);
#endif
}
__device__ __forceinline__ float log2f_fast(float x) {
#if __has_builtin(__builtin_amdgcn_logf)
  return __builtin_amdgcn_logf(x);
#else
  return __log2f(x);
#endif
}

// POLY pre-scaled log2-domain ssp: a = log2e*x; returns log2(0.5*2^a+0.5)
// = a/2 + E(a^2), E(u) = u*(c1 + u*(c2 + u*c3)) fit at u={1,4,9}.
// err <= ~3e-4 for |a| <= 3.5 (exact at a=0; even+odd structure exact).
__device__ __forceinline__ float ssp_poly(float a) {
  const float u = a * a;
  const float E =
      u * fmaf(u, fmaf(u, 3.553873e-5f, -1.6711860e-3f), 8.6598148e-2f);
  return fmaf(a, 0.5f, E);
}
// exact natural-domain variant (epilogue only, 2 calls/thread)
__device__ __forceinline__ float ssp_l2(float x) {
  const float a = 1.44269504f * x;
  return log2f_fast(fmaf(0.5f, exp2f_fast(a), 0.5f));
}

__device__ __forceinline__ f16x2 pk2(float a, float b) {
#if __has_builtin(__builtin_amdgcn_cvt_pkrtz)
  return __builtin_bit_cast(f16x2, __builtin_amdgcn_cvt_pkrtz(a, b));
#else
  f16x2 t;
  t.x = (_Float16)a;
  t.y = (_Float16)b;
  return t;
#endif
}

// rbf A-fragment for k-base kk*32+lq*8 via exact exp recurrence:
// a_j = -10*(x0-0.1j)^2; a_{j+1}-a_j = 2x0-0.2j-0.1 -> v*=r, r*=e^-0.2.
// Underflow -> exact 0 (values outside window are < 1e-19).
__device__ __forceinline__ f16x8 rbf8(float dd, int kk, int lq) {
  const float x0 = dd - 0.1f * (float)(kk * 32 + lq * 8);
  float v = exp2f_fast(-14.4269504f * x0 * x0);                // e^{a_0}
  float r = exp2f_fast(fmaf(2.88539008f, x0, -0.144269504f));  // e^{2x0-0.1}
  float w0 = v;
  v *= r; r *= 0.818730753f; float w1 = v;
  v *= r; r *= 0.818730753f; float w2 = v;
  v *= r; r *= 0.818730753f; float w3 = v;
  v *= r; r *= 0.818730753f; float w4 = v;
  v *= r; r *= 0.818730753f; float w5 = v;
  v *= r; r *= 0.818730753f; float w6 = v;
  v *= r;                    float w7 = v;
  union { f16x8 v8; f16x2 p[4]; } u;
  u.p[0] = pk2(w0, w1);
  u.p[1] = pk2(w2, w3);
  u.p[2] = pk2(w4, w5);
  u.p[3] = pk2(w6, w7);
  return u.v8;
}

// Pack log2e*W1 [300,128] -> f16 B-frag layout [10kk][8nt][64l][8j] at ws[0..40960)
// and W2 [128,128] -> [4kk][8nt][64l][8j] at ws[40960..57344).
// One thread per fragment row (8 j's): coalesced-ish 64B-segment reads, 16B writes.
__global__ void prep_pack(const float* __restrict__ W1, const float* __restrict__ W2,
                          unsigned short* __restrict__ ws) {
  const int gid = blockIdx.x * 256 + threadIdx.x;  // 7168 fragment rows total
  if (gid >= 7168) return;
  const int l = gid & 63;
  union { unsigned short s[8]; uint4 v; } u;
  if (gid < 5120) {  // W1 region: gid = (kk*8+ntg)*64 + l
    const int ntg = (gid >> 6) & 7, kk = gid >> 9;
    const int kbase = kk * 32 + ((l >> 4) << 3);
    const int h = ntg * 16 + (l & 15);
#pragma unroll
    for (int j = 0; j < 8; ++j) {
      const int k = kbase + j;
      const float f = (k < 300) ? 1.44269504f * W1[k * 128 + h] : 0.f;
      u.s[j] = __builtin_bit_cast(unsigned short, (_Float16)f);
    }
  } else {  // W2 region
    const int g2 = gid - 5120;
    const int ntg = (g2 >> 6) & 7, kk = g2 >> 9;
    const int kbase = kk * 32 + ((l >> 4) << 3);
    const int h = ntg * 16 + (l & 15);
#pragma unroll
    for (int j = 0; j < 8; ++j) {
      const int k = kbase + j;
      u.s[j] = __builtin_bit_cast(unsigned short, (_Float16)W2[k * 128 + h]);
    }
  }
  *(uint4*)(ws + gid * 8) = u.v;
}

__global__ __launch_bounds__(512, 4) void interaction_kernel(
    const float* __restrict__ nodef, const float* __restrict__ pos,
    const float* __restrict__ valid, const unsigned short* __restrict__ ws,
    const float* __restrict__ Wa1, const float* __restrict__ Wa2,
    const float* __restrict__ Wa3, float* __restrict__ out) {
  __shared__ __align__(16) _Float16 ytile[128 * 136];     // 34,816 B; wave-private rows
  __shared__ __align__(16) unsigned short W2pk[16384];    // 32,768 B
  __shared__ float d_lds[256];
  __shared__ __align__(16) int k0arr[256];
  __shared__ unsigned short jord[256];
  __shared__ unsigned short pr[2][256];
  __shared__ int kklo[16], kkhi[16];
  __shared__ float xrow[128], h1row[128], hhrow[128], a2row[128];
  __shared__ float partial[4][128];

  const int t = threadIdx.x;
  const int bid = blockIdx.x;  // b*256 + i
  const int b = bid >> 8;

  // ---- stage W2 fragments into LDS (16B coalesced) ----
  {
    const uint4* src = (const uint4*)(ws + 40960);
    uint4* d2 = (uint4*)W2pk;
    for (int i = t; i < 2048; i += 512) d2[i] = src[i];
  }
  if (t < 128) xrow[t] = nodef[bid * 128 + t];
  if (t < 256) {
    const float qx = pos[bid * 3 + 0], qy = pos[bid * 3 + 1], qz = pos[bid * 3 + 2];
    const float px = pos[(b * 256 + t) * 3 + 0];
    const float py = pos[(b * 256 + t) * 3 + 1];
    const float pz = pos[(b * 256 + t) * 3 + 2];
    const float dx = px - qx, dy = py - qy, dz = pz - qz;
    const float dd = sqrtf(dx * dx + dy * dy + dz * dz);
    d_lds[t] = dd;
    k0arr[t] = __float2int_rn(dd * 10.f);
  }
  __syncthreads();

  // ---- rank-sort, vectorized: 512 threads, each scans 128 entries as 32
  //      int4 broadcast reads (identical comparisons -> identical jord) ----
  {
    const int j = t & 255, half = t >> 8;
    const int key = k0arr[j];
    int rank = 0;
    const int4* kv = (const int4*)k0arr;
    const int mbase = half * 32, jbase = half * 128;
#pragma unroll 8
    for (int m = 0; m < 32; ++m) {
      const int4 v4 = kv[mbase + m];
      const int j2 = jbase + m * 4;
      rank += (v4.x < key || (v4.x == key && j2 + 0 < j)) ? 1 : 0;
      rank += (v4.y < key || (v4.y == key && j2 + 1 < j)) ? 1 : 0;
      rank += (v4.z < key || (v4.z == key && j2 + 2 < j)) ? 1 : 0;
      rank += (v4.w < key || (v4.w == key && j2 + 3 < j)) ? 1 : 0;
    }
    pr[half][j] = (unsigned short)rank;
  }
  // h1 = x @ Wa1 (partials over 4 thread-groups; overlaps the sort)
  {
    const int hh_ = t & 127, part = t >> 7;
    float a = 0.f;
#pragma unroll 8
    for (int k = part * 32; k < part * 32 + 32; ++k) a += xrow[k] * Wa1[k * 128 + hh_];
    partial[part][hh_] = a;
  }
  __syncthreads();
  if (t < 256) jord[pr[0][t] + pr[1][t]] = (unsigned short)t;
  if (t < 128)
    h1row[t] = partial[0][t] + partial[1][t] + partial[2][t] + partial[3][t];
  __syncthreads();
  // per sorted-16-group K-step ranges (window +-10: edge rbf e^-10 = 4.5e-5)
  if (t < 16) {
    const int base = t * 16;
    const int klo = max(0, k0arr[jord[base]] - 10);
    const int khi = min(319, k0arr[jord[base + 15]] + 10);
    kklo[t] = klo >> 5;
    kkhi[t] = (khi >> 5) + 1;
  }
  __syncthreads();

  const int w = t >> 6, l = t & 63;
  const int lr = l & 15, lq = l >> 4;
  float sumv[8];
#pragma unroll
  for (int r = 0; r < 8; ++r) sumv[r] = 0.f;
  f32x4 acc[4];  // ONE accumulator set, reused by every GEMM pass (reg-lean)

  // ---- main loop: 2 outer iters x (wave-private 16 rows x 128 h). NO BARRIERS.
  for (int it = 0; it < 2; ++it) {
    const int g = it * 8 + w;  // this wave's sorted 16-row group
    const float dd = d_lds[jord[it * 128 + w * 16 + lr]];
    const int lo = kklo[g];
    const int n = kkhi[g] - lo;  // wave-uniform, 1..3

    // shorts-layout: ((lo*8 + hg*4 + nt)*64 + l)*8 = pbase + hg*2048 + nt*512
    // (+4096 per extra K-step)
    const unsigned short* pbase = &ws[((lo * 8) * 64 + l) * 8];

    // hg0 B-frag loads FIRST — flight hides under the rbf recurrence below
    const f16x8 c00 = *(const f16x8*)(pbase + 0 * 512);
    const f16x8 c01 = *(const f16x8*)(pbase + 1 * 512);
    const f16x8 c02 = *(const f16x8*)(pbase + 2 * 512);
    const f16x8 c03 = *(const f16x8*)(pbase + 3 * 512);
    f16x8 c10, c11, c12, c13;
    if (n > 1) {  // wave-uniform
      c10 = *(const f16x8*)(pbase + 4096 + 0 * 512);
      c11 = *(const f16x8*)(pbase + 4096 + 1 * 512);
      c12 = *(const f16x8*)(pbase + 4096 + 2 * 512);
      c13 = *(const f16x8*)(pbase + 4096 + 3 * 512);
    }
    const f16x8 af0 = rbf8(dd, lo, lq);
    f16x8 af1;
    if (n > 1) af1 = rbf8(dd, lo + 1, lq);

    // ---- GEMM1 hg=0 ----
#pragma unroll
    for (int r = 0; r < 4; ++r) acc[r] = f32x4{0, 0, 0, 0};
    acc[0] = __builtin_amdgcn_mfma_f32_16x16x32_f16(af0, c00, acc[0], 0, 0, 0);
    acc[1] = __builtin_amdgcn_mfma_f32_16x16x32_f16(af0, c01, acc[1], 0, 0, 0);
    acc[2] = __builtin_amdgcn_mfma_f32_16x16x32_f16(af0, c02, acc[2], 0, 0, 0);
    acc[3] = __builtin_amdgcn_mfma_f32_16x16x32_f16(af0, c03, acc[3], 0, 0, 0);
    if (n > 1) {
      acc[0] = __builtin_amdgcn_mfma_f32_16x16x32_f16(af1, c10, acc[0], 0, 0, 0);
      acc[1] = __builtin_amdgcn_mfma_f32_16x16x32_f16(af1, c11, acc[1], 0, 0, 0);
      acc[2] = __builtin_amdgcn_mfma_f32_16x16x32_f16(af1, c12, acc[2], 0, 0, 0);
      acc[3] = __builtin_amdgcn_mfma_f32_16x16x32_f16(af1, c13, acc[3], 0, 0, 0);
    }
    for (int kk = lo + 2; kk < lo + n; ++kk) {  // rare (n>=3)
      const unsigned short* p = pbase + (kk - lo) * 4096;
      const f16x8 e0 = *(const f16x8*)(p + 0 * 512);
      const f16x8 e1 = *(const f16x8*)(p + 1 * 512);
      const f16x8 e2 = *(const f16x8*)(p + 2 * 512);
      const f16x8 e3 = *(const f16x8*)(p + 3 * 512);
      const f16x8 af = rbf8(dd, kk, lq);
      acc[0] = __builtin_amdgcn_mfma_f32_16x16x32_f16(af, e0, acc[0], 0, 0, 0);
      acc[1] = __builtin_amdgcn_mfma_f32_16x16x32_f16(af, e1, acc[1], 0, 0, 0);
      acc[2] = __builtin_amdgcn_mfma_f32_16x16x32_f16(af, e2, acc[2], 0, 0, 0);
      acc[3] = __builtin_amdgcn_mfma_f32_16x16x32_f16(af, e3, acc[3], 0, 0, 0);
    }
    // hg1 loads issued here — flight hides under hg0's poly+write tail
    const f16x8 d00 = *(const f16x8*)(pbase + 2048 + 0 * 512);
    const f16x8 d01 = *(const f16x8*)(pbase + 2048 + 1 * 512);
    const f16x8 d02 = *(const f16x8*)(pbase + 2048 + 2 * 512);
    const f16x8 d03 = *(const f16x8*)(pbase + 2048 + 3 * 512);
    f16x8 d10, d11, d12, d13;
    if (n > 1) {
      d10 = *(const f16x8*)(pbase + 2048 + 4096 + 0 * 512);
      d11 = *(const f16x8*)(pbase + 2048 + 4096 + 1 * 512);
      d12 = *(const f16x8*)(pbase + 2048 + 4096 + 2 * 512);
      d13 = *(const f16x8*)(pbase + 2048 + 4096 + 3 * 512);
    }
    // hg0 poly + write to wave-private ytile rows (in-wave order; no barrier)
#pragma unroll
    for (int nt = 0; nt < 4; ++nt)
#pragma unroll
      for (int r = 0; r < 4; ++r)
        ytile[(w * 16 + lq * 4 + r) * 136 + 0 * 64 + nt * 16 + lr] =
            (_Float16)ssp_poly(acc[nt][r]);

    // ---- GEMM1 hg=1 ----
#pragma unroll
    for (int r = 0; r < 4; ++r) acc[r] = f32x4{0, 0, 0, 0};
    acc[0] = __builtin_amdgcn_mfma_f32_16x16x32_f16(af0, d00, acc[0], 0, 0, 0);
    acc[1] = __builtin_amdgcn_mfma_f32_16x16x32_f16(af0, d01, acc[1], 0, 0, 0);
    acc[2] = __builtin_amdgcn_mfma_f32_16x16x32_f16(af0, d02, acc[2], 0, 0, 0);
    acc[3] = __builtin_amdgcn_mfma_f32_16x16x32_f16(af0, d03, acc[3], 0, 0, 0);
    if (n > 1) {
      acc[0] = __builtin_amdgcn_mfma_f32_16x16x32_f16(af1, d10, acc[0], 0, 0, 0);
      acc[1] = __builtin_amdgcn_mfma_f32_16x16x32_f16(af1, d11, acc[1], 0, 0, 0);
      acc[2] = __builtin_amdgcn_mfma_f32_16x16x32_f16(af1, d12, acc[2], 0, 0, 0);
      acc[3] = __builtin_amdgcn_mfma_f32_16x16x32_f16(af1, d13, acc[3], 0, 0, 0);
    }
    for (int kk = lo + 2; kk < lo + n; ++kk) {  // rare (n>=3)
      const unsigned short* p = pbase + 2048 + (kk - lo) * 4096;
      const f16x8 e0 = *(const f16x8*)(p + 0 * 512);
      const f16x8 e1 = *(const f16x8*)(p + 1 * 512);
      const f16x8 e2 = *(const f16x8*)(p + 2 * 512);
      const f16x8 e3 = *(const f16x8*)(p + 3 * 512);
      const f16x8 af = rbf8(dd, kk, lq);
      acc[0] = __builtin_amdgcn_mfma_f32_16x16x32_f16(af, e0, acc[0], 0, 0, 0);
      acc[1] = __builtin_amdgcn_mfma_f32_16x16x32_f16(af, e1, acc[1], 0, 0, 0);
      acc[2] = __builtin_amdgcn_mfma_f32_16x16x32_f16(af, e2, acc[2], 0, 0, 0);
      acc[3] = __builtin_amdgcn_mfma_f32_16x16x32_f16(af, e3, acc[3], 0, 0, 0);
    }
#pragma unroll
    for (int nt = 0; nt < 4; ++nt)
#pragma unroll
      for (int r = 0; r < 4; ++r)
        ytile[(w * 16 + lq * 4 + r) * 136 + 1 * 64 + nt * 16 + lr] =
            (_Float16)ssp_poly(acc[nt][r]);

    // GEMM2: two sequential hg2 passes, acc[4] reused; A-frags from OWN rows
    // (lgkmcnt orders the prior ds_writes; no barrier).
#pragma unroll
    for (int hg2 = 0; hg2 < 2; ++hg2) {
#pragma unroll
      for (int r = 0; r < 4; ++r) acc[r] = f32x4{0, 0, 0, 0};
#pragma unroll
      for (int kk = 0; kk < 4; ++kk) {
        const f16x8 afr =
            *(const f16x8*)&ytile[(w * 16 + lr) * 136 + kk * 32 + lq * 8];
#pragma unroll
        for (int nt = 0; nt < 4; ++nt) {
          const f16x8 bfr =
              *(const f16x8*)&W2pk[((kk * 8 + hg2 * 4 + nt) * 64 + l) * 8];
          acc[nt] = __builtin_amdgcn_mfma_f32_16x16x32_f16(afr, bfr, acc[nt], 0, 0, 0);
        }
      }
      // accumulate sum_j in log2 domain (ln2 applied once in the reduction)
#pragma unroll
      for (int nt = 0; nt < 4; ++nt)
#pragma unroll
        for (int r = 0; r < 4; ++r) sumv[hg2 * 4 + nt] += ssp_poly(acc[nt][r]);
    }
  }

  // ---- reduce sum_j partials: 8 waves x 4 lq = 32 rows per h-column.
  // Reuse ytile as f32 scratch; 2-stage tree (512 x 8 + 128 x 4).
  __syncthreads();
  {
    float* red = (float*)&ytile[0];
#pragma unroll
    for (int q = 0; q < 8; ++q) {
      const int hg2 = q >> 2, nt = q & 3;
      red[(w * 4 + lq) * 128 + hg2 * 64 + nt * 16 + lr] = 0.69314718f * sumv[q];
    }
  }
  __syncthreads();
  {
    const float* red = (const float*)&ytile[0];
    const int hh_ = t & 127, seg = t >> 7;  // seg 0..3 sums rows seg*8..seg*8+7
    float s = 0.f;
#pragma unroll
    for (int q = seg * 8; q < seg * 8 + 8; ++q) s += red[q * 128 + hh_];
    partial[seg][hh_] = s;
  }
  __syncthreads();
  if (t < 128) {
    const float s = partial[0][t] + partial[1][t] + partial[2][t] + partial[3][t];
    hhrow[t] = h1row[t] * s;  // CFConv: h * sum_j filt
  }
  __syncthreads();
  // a2 = ssp(hh @ Wa2) — unroll 32: all loads hoist ahead of the FMA chain
  {
    const int hh_ = t & 127, part = t >> 7;
    float a = 0.f;
#pragma unroll 32
    for (int k = part * 32; k < part * 32 + 32; ++k) a += hhrow[k] * Wa2[k * 128 + hh_];
    partial[part][hh_] = a;
  }
  __syncthreads();
  if (t < 128)
    a2row[t] = 0.69314718f *
               ssp_l2(partial[0][t] + partial[1][t] + partial[2][t] + partial[3][t]);
  __syncthreads();
  // out = x + (a2 @ Wa3) * valid — unroll 32
  {
    const int hh_ = t & 127, part = t >> 7;
    float a = 0.f;
#pragma unroll 32
    for (int k = part * 32; k < part * 32 + 32; ++k) a += a2row[k] * Wa3[k * 128 + hh_];
    partial[part][hh_] = a;
  }
  __syncthreads();
  if (t < 128)
    out[bid * 128 + t] =
        xrow[t] + (partial[0][t] + partial[1][t] + partial[2][t] + partial[3][t]) * valid[bid];
}

extern "C" void kernel_launch(void* const* d_in, const int* in_sizes, int n_in,
                              void* d_out, int out_size, void* d_ws, size_t ws_size,
                              hipStream_t stream) {
  const float* nodef = (const float*)d_in[0];
  const float* pos   = (const float*)d_in[1];
  const float* valid = (const float*)d_in[2];
  const float* W1    = (const float*)d_in[3];
  const float* W2    = (const float*)d_in[4];
  const float* Wa1   = (const float*)d_in[5];
  const float* Wa2   = (const float*)d_in[6];
  const float* Wa3   = (const float*)d_in[7];
  float* outp = (float*)d_out;
  unsigned short* wsp = (unsigned short*)d_ws;  // 57,344 f16 = 114,688 B

  prep_pack<<<28, 256, 0, stream>>>(W1, W2, wsp);
  interaction_kernel<<<1024, 512, 0, stream>>>(nodef, pos, valid, wsp,
                                               Wa1, Wa2, Wa3, outp);
}